// Round 9
// baseline (2300.169 us; speedup 1.0000x reference)
//
#include <hip/hip_runtime.h>

typedef unsigned int   u32;
typedef unsigned long long u64;
typedef float pkf2 __attribute__((ext_vector_type(2)));

#define B_  16
#define N_  8192
#define S_  1024
#define NS_ 32
#define XS_ 68   // [n][c] LDS row stride in floats (quad stride 17)
#define NWORK_ 240
#define NCHUNK_ 4096   // 1024 s-values x 4 b-groups; each chunk = 4 tiles (one per subgroup)

__device__ __forceinline__ float nanguard(float v) {
  u32 x = __float_as_uint(v);
  if ((x & 0x7F80u) == 0x7F80u) x ^= 0x0080u;
  return __uint_as_float(x);
}

// wave64 max via DPP (rocPRIM pattern)
__device__ __forceinline__ float wave_max_nonneg(float v) {
  int x = __float_as_int(v);
#define DPP_STEP(ctrl) \
  x = __float_as_int(fmaxf(__int_as_float(x), \
      __int_as_float(__builtin_amdgcn_update_dpp(0, x, (ctrl), 0xf, 0xf, true))))
  DPP_STEP(0x111);  // row_shr:1
  DPP_STEP(0x112);  // row_shr:2
  DPP_STEP(0x114);  // row_shr:4
  DPP_STEP(0x118);  // row_shr:8
  DPP_STEP(0x142);  // row_bcast15
  DPP_STEP(0x143);  // row_bcast31
#undef DPP_STEP
  return __int_as_float(__builtin_amdgcn_readlane(x, 63));
}

// ---------------- K0a: xyz (B,3,N) -> (B,N,4) f32 (+ zero sync counters) -----
// prog[0..15] = per-batch fps progress; prog[16] = worker-done; prog[17] = sig-done.
__global__ __launch_bounds__(256) void k_xyzt(const float* __restrict__ xyz, float4* __restrict__ xyzt,
                                              u32* __restrict__ prog) {
  if (blockIdx.x == 0 && blockIdx.y == 0 && threadIdx.x < 18) prog[threadIdx.x] = 0u;
  int b = blockIdx.y;
  int i = blockIdx.x * 256 + threadIdx.x;
  const float* p = xyz + (size_t)b * 3 * N_;
  xyzt[(size_t)b * N_ + i] = make_float4(p[i], p[N_ + i], p[2 * N_ + i], 0.f);
}

// ---------------- K0b: points (B,64,N) -> (B,N,64) f32 ----------------
__global__ __launch_bounds__(256) void k_ptst(const float* __restrict__ pts, float* __restrict__ ptst) {
  __shared__ float tile[64][65];
  int b = blockIdx.y, n0 = blockIdx.x * 64, t = threadIdx.x;
  {
    int c = t >> 2, j0 = (t & 3) * 16;
    const float4* src = (const float4*)(pts + (size_t)b * 64 * N_ + (size_t)c * N_ + n0 + j0);
#pragma unroll
    for (int q = 0; q < 4; ++q) {
      float4 a = src[q];
      tile[c][j0 + 4*q + 0] = a.x; tile[c][j0 + 4*q + 1] = a.y;
      tile[c][j0 + 4*q + 2] = a.z; tile[c][j0 + 4*q + 3] = a.w;
    }
  }
  __syncthreads();
  {
    int n = t >> 2, c0 = (t & 3) * 16;
    float4* dv = (float4*)(ptst + ((size_t)b * N_ + n0 + n) * 64 + c0);
#pragma unroll
    for (int q = 0; q < 4; ++q)
      dv[q] = make_float4(tile[c0 + 4*q + 0][n], tile[c0 + 4*q + 1][n],
                          tile[c0 + 4*q + 2][n], tile[c0 + 4*q + 3][n]);
  }
}

// ---------------- fallback K1: furthest point sampling (r12 verbatim) --------
__global__ __launch_bounds__(1024)
__attribute__((amdgpu_waves_per_eu(4, 4)))
void k_fps(const float4* __restrict__ xyzt,
           float4* __restrict__ nxf,
           float* __restrict__ out_xyz) {
#pragma clang fp contract(off)
  __shared__ float4 ldsp[N_];
  __shared__ u64 slot[4];
  __shared__ int win_hist[S_];
  int b = blockIdx.x, t = threadIdx.x;
  const float4* p4 = xyzt + (size_t)b * N_;
  const float4* pp8 = p4 + t * 8;

  float4 q0 = pp8[0], q1 = pp8[1], q2 = pp8[2], q3 = pp8[3];
  float4 q4 = pp8[4], q5 = pp8[5], q6 = pp8[6], q7 = pp8[7];
  ldsp[t * 8 + 0] = q0; ldsp[t * 8 + 1] = q1; ldsp[t * 8 + 2] = q2; ldsp[t * 8 + 3] = q3;
  ldsp[t * 8 + 4] = q4; ldsp[t * 8 + 5] = q5; ldsp[t * 8 + 6] = q6; ldsp[t * 8 + 7] = q7;

#define DECLPAIR(P, A, B) \
  pkf2 px##P = {q##A.x, q##B.x}; pkf2 py##P = {q##A.y, q##B.y}; \
  pkf2 pz##P = {q##A.z, q##B.z}; pkf2 dm##P = {1e10f, 1e10f};
  DECLPAIR(01, 0, 1) DECLPAIR(23, 2, 3) DECLPAIR(45, 4, 5) DECLPAIR(67, 6, 7)
#undef DECLPAIR
#define PIN(P) asm volatile("" : "+v"(px##P), "+v"(py##P), "+v"(pz##P));
  PIN(01) PIN(23) PIN(45) PIN(67)
#undef PIN

  if (t == 0) {
    slot[0] = 8191ull;
    slot[1] = 0; slot[2] = 0; slot[3] = 0;
    win_hist[0] = 0;
  }
  __syncthreads();
  int lane = t & 63;
  for (int it = 1; it < S_; ++it) {
    u64 w = slot[(it - 1) & 3];
    int widx = 8191 - (int)(w & 0xFFFFFFFFull);
    if (t == 0) { win_hist[it - 1] = widx; slot[(it + 1) & 3] = 0; }
    float4 c = ldsp[widx & (N_ - 1)];
    pkf2 cx2 = {c.x, c.x}, cy2 = {c.y, c.y}, cz2 = {c.z, c.z};
#define UPDP(P) { \
    pkf2 dx = px##P - cx2; pkf2 dy = py##P - cy2; pkf2 dz = pz##P - cz2; \
    pkf2 xx = dx * dx; pkf2 yy = dy * dy; pkf2 zz = dz * dz; \
    pkf2 ss = xx + yy; pkf2 dd = ss + zz; \
    dm##P.x = fminf(dm##P.x, dd.x); dm##P.y = fminf(dm##P.y, dd.y); }
    UPDP(01) UPDP(23) UPDP(45) UPDP(67)
#undef UPDP
    float e0 = dm01.x, e1 = dm01.y, e2 = dm23.x, e3 = dm23.y;
    float e4 = dm45.x, e5 = dm45.y, e6 = dm67.x, e7 = dm67.y;
    float va0 = e1 > e0 ? e1 : e0; int ia0 = e1 > e0 ? 1 : 0;
    float va1 = e3 > e2 ? e3 : e2; int ia1 = e3 > e2 ? 3 : 2;
    float va2 = e5 > e4 ? e5 : e4; int ia2 = e5 > e4 ? 5 : 4;
    float va3 = e7 > e6 ? e7 : e6; int ia3 = e7 > e6 ? 7 : 6;
    float vb0 = va1 > va0 ? va1 : va0; int ib0 = va1 > va0 ? ia1 : ia0;
    float vb1 = va3 > va2 ? va3 : va2; int ib1 = va3 > va2 ? ia3 : ia2;
    float bv = vb1 > vb0 ? vb1 : vb0;  int bk = vb1 > vb0 ? ib1 : ib0;
    int bi = t * 8 + bk;
    float wm = wave_max_nonneg(bv);
    u64 msk = __ballot(bv == wm);
    int wl = __ffsll((long long)msk) - 1;
    int wbi = __builtin_amdgcn_readlane(bi, wl);
    if (lane == 0)
      atomicMax(&slot[it & 3],
                ((u64)__float_as_uint(wm) << 32) | (u64)(u32)(8191 - wbi));
    __syncthreads();
  }
  if (t == 0)
    win_hist[S_ - 1] = 8191 - (int)(slot[(S_ - 1) & 3] & 0xFFFFFFFFull);
  __syncthreads();
  {
    int wi = win_hist[t] & (N_ - 1);
    float4 c = ldsp[wi];
    nxf[(size_t)b * S_ + t] = c;
    float* o = out_xyz + (size_t)b * 3 * S_;
    o[t] = nanguard(c.x); o[S_ + t] = nanguard(c.y); o[2 * S_ + t] = nanguard(c.z);
  }
}

// ---------------- fallback K2: ball query ----------------
__global__ __launch_bounds__(256) void k_ball(const float4* __restrict__ xyzt,
                                              const float4* __restrict__ nxf,
                                              int* __restrict__ ballidx) {
  int gw = blockIdx.x * 4 + (threadIdx.x >> 6);
  int lane = threadIdx.x & 63;
  int b = gw >> 10, s = gw & 1023;
  float4 c = nxf[(size_t)b * S_ + s];
  const float4* pts = xyzt + (size_t)b * N_;
  int* out = ballidx + (size_t)gw * NS_;
  int cnt = 0, first = 0;
  bool havefirst = false;
  for (int chunk = 0; chunk < N_; chunk += 64) {
    float4 p = pts[chunk + lane];
    float dx = p.x - c.x, dy = p.y - c.y, dz = p.z - c.z;
    float d2 = __fadd_rn(__fadd_rn(__fmul_rn(dx, dx), __fmul_rn(dy, dy)), __fmul_rn(dz, dz));
    bool v = d2 <= 0.04f;
    u64 m = __ballot(v);
    if (m) {
      int pos = cnt + __popcll(m & ((1ull << lane) - 1ull));
      if (v && pos < NS_) out[pos] = chunk + lane;
      if (!havefirst) { first = chunk + (__ffsll((long long)m) - 1); havefirst = true; }
      cnt += __popcll(m);
      if (cnt >= NS_) break;
    }
  }
  if (cnt < NS_) {
    for (int p = cnt + lane; p < NS_; p += 64) out[p] = first;
  }
}

// ---------------- chain machinery (fallback path, r10 verbatim) --------------
struct ChainSm {
  float Wbuf[64 * XS_];
  float W1f[64 * 9];
  float W0f[8 * 4];
  float s2f[64], sm0f[64], sm1f[64];
  float bb0[8];
  float bb1[64], bb2[64], bm0[64], bm1[64];
  float X[32 * XS_];
  float H[32 * XS_];
  float scratch[384];
  int   idx_s[NS_];
};

__device__ __forceinline__ void stage_w64(float* Wbuf, const float* w, int t) {
  int c = t >> 2, q = (t & 3) * 16;
  const float4* src = (const float4*)(w + c * 64 + q);
  float4* dst = (float4*)(Wbuf + c * XS_ + q);
  dst[0] = src[0]; dst[1] = src[1]; dst[2] = src[2]; dst[3] = src[3];
}

template<bool RELU>
__device__ __forceinline__ void gemm64(const float* __restrict__ Wbuf,
                                       const float* __restrict__ Xin,
                                       float* __restrict__ Yout,
                                       const float* __restrict__ scl,
                                       const float* __restrict__ bia,
                                       int lane, int n0) {
  float acc[8] = {0,0,0,0,0,0,0,0};
#pragma unroll
  for (int k4 = 0; k4 < 16; ++k4) {
    float4 wq = *(const float4*)&Wbuf[lane * XS_ + k4 * 4];
#pragma unroll
    for (int nj = 0; nj < 8; ++nj) {
      float4 xq = *(const float4*)&Xin[(n0 + nj) * XS_ + k4 * 4];
      acc[nj] += wq.x * xq.x; acc[nj] += wq.y * xq.y;
      acc[nj] += wq.z * xq.z; acc[nj] += wq.w * xq.w;
    }
  }
  float sc = scl[lane], bi = bia[lane];
#pragma unroll
  for (int nj = 0; nj < 8; ++nj) {
    float v = sc * acc[nj] + bi;
    Yout[(n0 + nj) * XS_ + lane] = RELU ? fmaxf(v, 0.f) : v;
  }
}

template<bool USE_PTST>
__device__ __forceinline__ void chain_tile(ChainSm& sm, int b, int s, int bs,
    const float4* xyzt, const float* ptst, const float* points,
    const float4* nxf, const int* ballidx,
    const float* w0, const float* b0, const float* s0, const float* t0,
    const float* w1, const float* b1, const float* s1, const float* t1,
    const float* w2, const float* b2, const float* s2, const float* t2,
    const float* m0w, const float* m0b, const float* m0s, const float* m0t,
    const float* m1w, const float* m1b, const float* m1s, const float* m1t) {
  int t = threadIdx.x, lane = t & 63, g = t >> 6, n0 = g * 8;

  stage_w64(sm.Wbuf, w2, t);
  if (t < 64) {
    float v2 = s2[t];  sm.s2f[t] = v2;  sm.bb2[t] = v2 * b2[t] + t2[t];
    float vm0 = m0s[t]; sm.sm0f[t] = vm0; sm.bm0[t] = vm0 * m0b[t] + m0t[t];
    float vm1 = m1s[t]; sm.sm1f[t] = vm1; sm.bm1[t] = vm1 * m1b[t] + m1t[t];
    float v1 = s1[t];
#pragma unroll
    for (int k = 0; k < 8; ++k) sm.W1f[t * 9 + k] = v1 * w1[t * 8 + k];
    sm.bb1[t] = v1 * b1[t] + t1[t];
  }
  if (t < 8) {
    float v0 = s0[t];
#pragma unroll
    for (int k = 0; k < 3; ++k) sm.W0f[t * 4 + k] = v0 * w0[t * 3 + k];
    sm.bb0[t] = v0 * b0[t] + t0[t];
  }
  if (t < NS_) sm.idx_s[t] = ballidx[(size_t)bs * NS_ + t] & (N_ - 1);
  __syncthreads();                                   // B1

  {
    int n = t >> 3, c8 = (t & 7) * 8;
    int pi = sm.idx_s[n];
    if (USE_PTST) {
      const float4* v = (const float4*)(ptst + ((size_t)b * N_ + pi) * 64 + c8);
      float4* xr = (float4*)&sm.X[n * XS_ + c8];
      xr[0] = v[0]; xr[1] = v[1];
    } else {
      const float* pp = points + (size_t)b * 64 * N_ + (size_t)c8 * N_ + pi;
#pragma unroll
      for (int j = 0; j < 8; ++j) sm.X[n * XS_ + c8 + j] = pp[(size_t)j * N_];
    }
  }
  if (t < NS_) {
    float4 p = xyzt[(size_t)b * N_ + sm.idx_s[t]];
    float4 cc = nxf[(size_t)b * S_ + s];
    float* gx = &sm.scratch[256 + t * 4];
    gx[0] = p.x - cc.x; gx[1] = p.y - cc.y; gx[2] = p.z - cc.z;
  }
  __syncthreads();                                   // B2

  {
    int n = t >> 3, cc = t & 7;
    const float* gx = &sm.scratch[256 + n * 4];
    float a = sm.bb0[cc];
    a += sm.W0f[cc * 4 + 0] * gx[0];
    a += sm.W0f[cc * 4 + 1] * gx[1];
    a += sm.W0f[cc * 4 + 2] * gx[2];
    sm.scratch[n * 8 + cc] = fmaxf(a, 0.f);
  }
  {
#pragma unroll
    for (int nj = 0; nj < 8; ++nj) {
      float a = sm.bb1[lane];
      const float* p8 = &sm.scratch[(n0 + nj) * 8];
#pragma unroll
      for (int k = 0; k < 8; ++k) a += sm.W1f[lane * 9 + k] * p8[k];
      sm.X[(n0 + nj) * XS_ + lane] += a;
    }
  }
  gemm64<false>(sm.Wbuf, sm.X, sm.H, sm.s2f, sm.bb2, lane, n0);
  __syncthreads();                                   // B3
  stage_w64(sm.Wbuf, m0w, t);
  __syncthreads();                                   // B4
  gemm64<true>(sm.Wbuf, sm.H, sm.X, sm.sm0f, sm.bm0, lane, n0);
  __syncthreads();                                   // B5
  stage_w64(sm.Wbuf, m1w, t);
  __syncthreads();                                   // B6
  gemm64<true>(sm.Wbuf, sm.X, sm.H, sm.sm1f, sm.bm1, lane, n0);
}

// ---------------- fallback K3: chain pass ----------------
template<bool USE_PTST, bool WRITE_H2>
__global__ __launch_bounds__(256) void k_chain(
    const float4* __restrict__ xyzt, const float* __restrict__ ptst,
    const float* __restrict__ points,
    const float4* __restrict__ nxf, const int* __restrict__ ballidx,
    const float* w0, const float* b0, const float* s0, const float* t0,
    const float* w1, const float* b1, const float* s1, const float* t1,
    const float* w2, const float* b2, const float* s2, const float* t2,
    const float* m0w, const float* m0b, const float* m0s, const float* m0t,
    const float* m1w, const float* m1b, const float* m1s, const float* m1t,
    float* __restrict__ h2out, float* __restrict__ partials) {
  __shared__ ChainSm sm;
  int t = threadIdx.x, bs = blockIdx.x;
  int b = bs >> 10, s = bs & 1023;
  int lane = t & 63, g = t >> 6, n0 = g * 8;

  chain_tile<USE_PTST>(sm, b, s, bs, xyzt, ptst, points, nxf, ballidx,
                       w0, b0, s0, t0, w1, b1, s1, t1, w2, b2, s2, t2,
                       m0w, m0b, m0s, m0t, m1w, m1b, m1s, m1t);

  float* psum = sm.scratch;
  float lsum = 0.f;
#pragma unroll
  for (int nj = 0; nj < 8; ++nj) {
    float r = sm.H[(n0 + nj) * XS_ + lane];
    lsum += r;
    if (WRITE_H2)
      h2out[((size_t)bs * 32 + n0 + nj) * 64 + lane] = r;
  }
  psum[lane * 5 + g] = lsum;
  __syncthreads();                                   // B7
  if (t < 64) {
    float v = (psum[t * 5 + 0] + psum[t * 5 + 1]) + (psum[t * 5 + 2] + psum[t * 5 + 3]);
    partials[(size_t)bs * 64 + t] = v;
  }
}

// ---------------- fully-fused fps + ball + chain + eca + final ---------------
// r8 post-mortem: fusion sync machinery correct, but phase D (4ch x 8row,
// 90 live regs) spilled against the kernel-wide 64-VGPR allocation ->
// FETCH/WRITE ballooned to 1.8/2.3 GB of scratch traffic, k_fused 2160us.
// Fix: phase D register blocking shrunk to 4ch x 4row, 2 row-halves x 2
// channel-halves sequential (peak live ~52 regs < 64). Per-element k4-order
// unchanged (bitwise-same); row-max carried across row-halves in pm[] (max
// is order-free). X read direct from L3-resident h2 (16-lane-broadcast).
struct ChainSub {
  float X[32 * XS_];
  float H[32 * XS_];
  float scratch[384];
  int   idx_s[NS_];
};
struct WkSm {
  float Wc2[64 * XS_];
  float Wm0[64 * XS_];
  float Wm1[64 * XS_];
  float W1f[64 * 9];
  float W0f[8 * 4];
  float s2f[64], sm0f[64], sm1f[64];
  float bb0[8];
  float bb1[64], bb2[64], bm0[64], bm1[64];
  ChainSub sub[4];
};
struct FpsSm {
  float4 ldsp[N_];
  u64 slot[4];
  int win_hist[S_];
};
struct FinSm {
  float Wh[128 * XS_];
  float esf[128], bbf[128];
  float sigl[64];
  float red[64 * 5];
  float yy[66];
};
union FusedSm { FpsSm f; WkSm w; FinSm fin; };
static_assert(sizeof(FusedSm) <= 160 * 1024, "LDS overflow");

__device__ __forceinline__ void final_phase(FinSm& fin, int t, int blkid, u32* prog,
    const float* __restrict__ h2, const float* __restrict__ sig,
    const float* __restrict__ ew, const float* __restrict__ es,
    const float* __restrict__ eb, const float* __restrict__ et,
    float* __restrict__ outf) {
  // stage ew/esf/bbf while (possibly) waiting for sig
  if (t < 256) {
    int c2 = t >> 1, h = (t & 1) * 32;
    const float4* src = (const float4*)(ew + c2 * 64 + h);
    float4* dst = (float4*)(fin.Wh + c2 * XS_ + h);
#pragma unroll
    for (int j = 0; j < 8; ++j) dst[j] = src[j];
  }
  if (t < 128) { float v = es[t]; fin.esf[t] = v; fin.bbf[t] = v * eb[t] + et[t]; }
  if (t == 0) {
    while (__hip_atomic_load(&prog[17], __ATOMIC_RELAXED, __HIP_MEMORY_SCOPE_AGENT) < 16u)
      __builtin_amdgcn_s_sleep(8);
    (void)__hip_atomic_load(&prog[17], __ATOMIC_ACQUIRE, __HIP_MEMORY_SCOPE_AGENT);
  }
  __syncthreads();
  if (t < 64) fin.sigl[t] = sig[(blkid >> 4) * 64 + t];   // block-uniform b
  __syncthreads();

  int wv = t >> 6, lane = t & 63;
  int cg = lane & 15, rg = lane >> 4;
#pragma unroll
  for (int it = 0; it < 4; ++it) {
    int bs = blkid * 64 + it * 16 + wv;
    int b = bs >> 10, s = bs & 1023;
    const float* hsrc = h2 + (size_t)bs * 2048;
#pragma unroll
    for (int half = 0; half < 2; ++half) {
      float pm0, pm1, pm2, pm3;
#pragma unroll
      for (int rh = 0; rh < 2; ++rh) {
        float acc[4][4];
#pragma unroll
        for (int i = 0; i < 4; ++i)
#pragma unroll
          for (int j = 0; j < 4; ++j) acc[i][j] = 0.f;
#pragma unroll
        for (int k4 = 0; k4 < 16; ++k4) {
          float4 sgl = *(const float4*)&fin.sigl[k4 * 4];   // LDS broadcast
          float4 xq[4];
#pragma unroll
          for (int j = 0; j < 4; ++j) {
            float4 v = *(const float4*)&hsrc[(size_t)(rg + 4 * (rh * 4 + j)) * 64 + k4 * 4];
            v.x *= sgl.x; v.y *= sgl.y; v.z *= sgl.z; v.w *= sgl.w;
            xq[j] = v;
          }
#pragma unroll
          for (int i = 0; i < 4; ++i) {
            float4 wq = *(const float4*)&fin.Wh[(half * 64 + cg + 16 * i) * XS_ + k4 * 4];
#pragma unroll
            for (int j = 0; j < 4; ++j) {
              acc[i][j] += wq.x * xq[j].x; acc[i][j] += wq.y * xq[j].y;
              acc[i][j] += wq.z * xq[j].z; acc[i][j] += wq.w * xq[j].w;
            }
          }
        }
#define RED(i, mv) { \
        float a0 = fmaxf(fmaxf(acc[i][0], acc[i][1]), fmaxf(acc[i][2], acc[i][3])); \
        mv = rh ? fmaxf(mv, a0) : a0; }
        RED(0, pm0) RED(1, pm1) RED(2, pm2) RED(3, pm3)
#undef RED
      }
      // cross-row-group max (lanes cg, cg+16, cg+32, cg+48 hold partials)
#define SHR(mv) { mv = fmaxf(mv, __shfl_xor(mv, 16)); mv = fmaxf(mv, __shfl_xor(mv, 32)); }
      SHR(pm0) SHR(pm1) SHR(pm2) SHR(pm3)
#undef SHR
      float msel = rg == 0 ? pm0 : rg == 1 ? pm1 : rg == 2 ? pm2 : pm3;
      int c = half * 64 + cg + 16 * rg;
      outf[((size_t)b * 128 + c) * S_ + s] = nanguard(fin.esf[c] * msel + fin.bbf[c]);
    }
  }
}

__global__ __launch_bounds__(1024)
__attribute__((amdgpu_waves_per_eu(4, 4)))
void k_fused(const float4* __restrict__ xyzt, const float* __restrict__ ptst,
             float4* __restrict__ nxf, float* __restrict__ out_xyz,
             u32* __restrict__ prog,
             const float* w0, const float* b0, const float* s0, const float* t0,
             const float* w1, const float* b1, const float* s1, const float* t1,
             const float* w2, const float* b2, const float* s2, const float* t2,
             const float* m0w, const float* m0b, const float* m0s, const float* m0t,
             const float* m1w, const float* m1b, const float* m1s, const float* m1t,
             float* __restrict__ h2out, float* __restrict__ partials,
             const float* __restrict__ ecak,
             const float* __restrict__ ew, const float* __restrict__ eb,
             const float* __restrict__ es, const float* __restrict__ et,
             float* __restrict__ sig, float* __restrict__ outf) {
  __shared__ FusedSm smu;
  int t = threadIdx.x;

  if (blockIdx.x < B_) {
    // ================= fps producer =================
#pragma clang fp contract(off)
    FpsSm& fs = smu.f;
    int b = blockIdx.x;
    const float4* p4 = xyzt + (size_t)b * N_;
    const float4* pp8 = p4 + t * 8;

    float4 q0 = pp8[0], q1 = pp8[1], q2 = pp8[2], q3 = pp8[3];
    float4 q4 = pp8[4], q5 = pp8[5], q6 = pp8[6], q7 = pp8[7];
    fs.ldsp[t * 8 + 0] = q0; fs.ldsp[t * 8 + 1] = q1; fs.ldsp[t * 8 + 2] = q2; fs.ldsp[t * 8 + 3] = q3;
    fs.ldsp[t * 8 + 4] = q4; fs.ldsp[t * 8 + 5] = q5; fs.ldsp[t * 8 + 6] = q6; fs.ldsp[t * 8 + 7] = q7;

#define DECLPAIR(P, A, B) \
    pkf2 px##P = {q##A.x, q##B.x}; pkf2 py##P = {q##A.y, q##B.y}; \
    pkf2 pz##P = {q##A.z, q##B.z}; pkf2 dm##P = {1e10f, 1e10f};
    DECLPAIR(01, 0, 1) DECLPAIR(23, 2, 3) DECLPAIR(45, 4, 5) DECLPAIR(67, 6, 7)
#undef DECLPAIR
#define PIN(P) asm volatile("" : "+v"(px##P), "+v"(py##P), "+v"(pz##P));
    PIN(01) PIN(23) PIN(45) PIN(67)
#undef PIN

    if (t == 0) {
      fs.slot[0] = 8191ull;
      fs.slot[1] = 0; fs.slot[2] = 0; fs.slot[3] = 0;
      fs.win_hist[0] = 0;
    }
    __syncthreads();
    int lane = t & 63;
    for (int it = 1; it < S_; ++it) {
      u64 w = fs.slot[(it - 1) & 3];
      int widx = 8191 - (int)(w & 0xFFFFFFFFull);
      float4 c = fs.ldsp[widx & (N_ - 1)];
      if (t == 0) {
        fs.win_hist[it - 1] = widx; fs.slot[(it + 1) & 3] = 0;
        if ((it & 15) == 0)
          __hip_atomic_store(&prog[b], (u32)(it - 1), __ATOMIC_RELEASE, __HIP_MEMORY_SCOPE_AGENT);
        nxf[(size_t)b * S_ + (it - 1)] = c;
      }
      pkf2 cx2 = {c.x, c.x}, cy2 = {c.y, c.y}, cz2 = {c.z, c.z};
#define UPDP(P) { \
      pkf2 dx = px##P - cx2; pkf2 dy = py##P - cy2; pkf2 dz = pz##P - cz2; \
      pkf2 xx = dx * dx; pkf2 yy = dy * dy; pkf2 zz = dz * dz; \
      pkf2 ss = xx + yy; pkf2 dd = ss + zz; \
      dm##P.x = fminf(dm##P.x, dd.x); dm##P.y = fminf(dm##P.y, dd.y); }
      UPDP(01) UPDP(23) UPDP(45) UPDP(67)
#undef UPDP
      float e0 = dm01.x, e1 = dm01.y, e2 = dm23.x, e3 = dm23.y;
      float e4 = dm45.x, e5 = dm45.y, e6 = dm67.x, e7 = dm67.y;
      float va0 = e1 > e0 ? e1 : e0; int ia0 = e1 > e0 ? 1 : 0;
      float va1 = e3 > e2 ? e3 : e2; int ia1 = e3 > e2 ? 3 : 2;
      float va2 = e5 > e4 ? e5 : e4; int ia2 = e5 > e4 ? 5 : 4;
      float va3 = e7 > e6 ? e7 : e6; int ia3 = e7 > e6 ? 7 : 6;
      float vb0 = va1 > va0 ? va1 : va0; int ib0 = va1 > va0 ? ia1 : ia0;
      float vb1 = va3 > va2 ? va3 : va2; int ib1 = va3 > va2 ? ia3 : ia2;
      float bv = vb1 > vb0 ? vb1 : vb0;  int bk = vb1 > vb0 ? ib1 : ib0;
      int bi = t * 8 + bk;
      float wm = wave_max_nonneg(bv);
      u64 msk = __ballot(bv == wm);
      int wl = __ffsll((long long)msk) - 1;
      int wbi = __builtin_amdgcn_readlane(bi, wl);
      if (lane == 0)
        atomicMax(&fs.slot[it & 3],
                  ((u64)__float_as_uint(wm) << 32) | (u64)(u32)(8191 - wbi));
      __syncthreads();
    }
    if (t == 0) {
      int wl_ = 8191 - (int)(fs.slot[(S_ - 1) & 3] & 0xFFFFFFFFull);
      fs.win_hist[S_ - 1] = wl_;
      float4 c = fs.ldsp[wl_ & (N_ - 1)];
      nxf[(size_t)b * S_ + (S_ - 1)] = c;
    }
    __syncthreads();
    {
      int wi = fs.win_hist[t] & (N_ - 1);
      float4 c = fs.ldsp[wi];
      float* o = out_xyz + (size_t)b * 3 * S_;
      o[t] = nanguard(c.x); o[S_ + t] = nanguard(c.y); o[2 * S_ + t] = nanguard(c.z);
    }
    if (t == 0)
      __hip_atomic_store(&prog[b], (u32)S_, __ATOMIC_RELEASE, __HIP_MEMORY_SCOPE_AGENT);

    // ---- phase C: eca for this block's b (exact k_eca replica, t<256) ----
    __syncthreads();                 // ldsp reads complete; FinSm overlay safe
    FinSm& fin = smu.fin;
    if (t == 0) {
      while (__hip_atomic_load(&prog[16], __ATOMIC_RELAXED, __HIP_MEMORY_SCOPE_AGENT) < (u32)NWORK_)
        __builtin_amdgcn_s_sleep(32);
      (void)__hip_atomic_load(&prog[16], __ATOMIC_ACQUIRE, __HIP_MEMORY_SCOPE_AGENT);
    }
    __syncthreads();
    if (t < 256) {
      int c = t & 63, sg = t >> 6;
      float acc = 0.f;
      for (int s2 = sg; s2 < S_; s2 += 4)
        acc += partials[((size_t)b * S_ + s2) * 64 + c];
      fin.red[c * 5 + sg] = acc;
    }
    __syncthreads();
    if (t < 64) {
      float v = (fin.red[t * 5 + 0] + fin.red[t * 5 + 1]) + (fin.red[t * 5 + 2] + fin.red[t * 5 + 3]);
      fin.yy[t + 1] = v * (1.f / 32768.f);
    }
    if (t == 64) { fin.yy[0] = 0.f; fin.yy[65] = 0.f; }
    __syncthreads();
    if (t < 64) {
      float gv = ecak[0] * fin.yy[t] + ecak[1] * fin.yy[t + 1] + ecak[2] * fin.yy[t + 2];
      sig[b * 64 + t] = 1.f / (1.f + expf(-gv));
    }
    __threadfence();
    __syncthreads();
    if (t == 0)
      __hip_atomic_fetch_add(&prog[17], 1u, __ATOMIC_RELEASE, __HIP_MEMORY_SCOPE_AGENT);
    final_phase(fin, t, blockIdx.x, prog, h2out, sig, ew, es, eb, et, outf);
    return;
  }

  // ================= worker =================
  WkSm& wk = smu.w;
  int w = blockIdx.x - B_;
  if (t < 256) {
    stage_w64(wk.Wc2, w2, t);
    stage_w64(wk.Wm0, m0w, t);
    stage_w64(wk.Wm1, m1w, t);
  }
  if (t < 64) {
    float v2 = s2[t];  wk.s2f[t] = v2;  wk.bb2[t] = v2 * b2[t] + t2[t];
    float vm0 = m0s[t]; wk.sm0f[t] = vm0; wk.bm0[t] = vm0 * m0b[t] + m0t[t];
    float vm1 = m1s[t]; wk.sm1f[t] = vm1; wk.bm1[t] = vm1 * m1b[t] + m1t[t];
    float v1 = s1[t];
#pragma unroll
    for (int k = 0; k < 8; ++k) wk.W1f[t * 9 + k] = v1 * w1[t * 8 + k];
    wk.bb1[t] = v1 * b1[t] + t1[t];
  }
  if (t < 8) {
    float v0 = s0[t];
#pragma unroll
    for (int k = 0; k < 3; ++k) wk.W0f[t * 4 + k] = v0 * w0[t * 3 + k];
    wk.bb0[t] = v0 * b0[t] + t0[t];
  }
  __syncthreads();

  int sg = t >> 8, tid = t & 255, lane = t & 63, g2 = (t >> 6) & 3, n0 = g2 * 8;
  ChainSub& cs = wk.sub[sg];

  for (int ck = w; ck < NCHUNK_; ck += NWORK_) {
    int s = ck >> 2, bg = ck & 3, b = bg * 4 + sg;
    if (t == 0) {
      int bbase = bg * 4;
#pragma unroll
      for (int j = 0; j < 4; ++j) {
        while (__hip_atomic_load(&prog[bbase + j], __ATOMIC_RELAXED, __HIP_MEMORY_SCOPE_AGENT) < (u32)(s + 1))
          __builtin_amdgcn_s_sleep(32);
      }
      (void)__hip_atomic_load(&prog[bbase], __ATOMIC_ACQUIRE, __HIP_MEMORY_SCOPE_AGENT);
    }
    __syncthreads();                                 // BAR A (data for s visible)

    float4 cc;
    if (g2 == 0) {
      cc = nxf[(size_t)b * S_ + s];
      const float4* pts = xyzt + (size_t)b * N_;
      int cnt = 0, first = 0;
      bool havefirst = false;
      for (int chunk = 0; chunk < N_; chunk += 64) {
        float4 p = pts[chunk + lane];
        float dx = p.x - cc.x, dy = p.y - cc.y, dz = p.z - cc.z;
        float d2 = __fadd_rn(__fadd_rn(__fmul_rn(dx, dx), __fmul_rn(dy, dy)), __fmul_rn(dz, dz));
        bool v = d2 <= 0.04f;
        u64 m = __ballot(v);
        if (m) {
          int pos = cnt + __popcll(m & ((1ull << lane) - 1ull));
          if (v && pos < NS_) cs.idx_s[pos] = chunk + lane;
          if (!havefirst) { first = chunk + (__ffsll((long long)m) - 1); havefirst = true; }
          cnt += __popcll(m);
          if (cnt >= NS_) break;
        }
      }
      if (cnt < NS_) {
        for (int p = cnt + lane; p < NS_; p += 64) cs.idx_s[p] = first;
      }
    }
    __syncthreads();                                 // BAR B (idx_s ready)

    {
      int n = tid >> 3, c8 = (tid & 7) * 8;
      int pi = cs.idx_s[n];
      const float4* v = (const float4*)(ptst + ((size_t)b * N_ + pi) * 64 + c8);
      float4* xr = (float4*)&cs.X[n * XS_ + c8];
      xr[0] = v[0]; xr[1] = v[1];
    }
    if (tid < NS_) {
      float4 p = xyzt[(size_t)b * N_ + cs.idx_s[tid]];
      float* gx = &cs.scratch[256 + tid * 4];
      gx[0] = p.x - cc.x; gx[1] = p.y - cc.y; gx[2] = p.z - cc.z;
    }
    __syncthreads();                                 // BAR C (GX cross-wave)

    {
      int n = tid >> 3, ch = tid & 7;
      const float* gx = &cs.scratch[256 + n * 4];
      float a = wk.bb0[ch];
      a += wk.W0f[ch * 4 + 0] * gx[0];
      a += wk.W0f[ch * 4 + 1] * gx[1];
      a += wk.W0f[ch * 4 + 2] * gx[2];
      cs.scratch[n * 8 + ch] = fmaxf(a, 0.f);
    }
    {
#pragma unroll
      for (int nj = 0; nj < 8; ++nj) {
        float a = wk.bb1[lane];
        const float* p8 = &cs.scratch[(n0 + nj) * 8];
#pragma unroll
        for (int k = 0; k < 8; ++k) a += wk.W1f[lane * 9 + k] * p8[k];
        cs.X[(n0 + nj) * XS_ + lane] += a;
      }
    }
    gemm64<false>(wk.Wc2, cs.X, cs.H, wk.s2f, wk.bb2, lane, n0);
    gemm64<true >(wk.Wm0, cs.H, cs.X, wk.sm0f, wk.bm0, lane, n0);
    gemm64<true >(wk.Wm1, cs.X, cs.H, wk.sm1f, wk.bm1, lane, n0);

    int bs = (b << 10) | s;
    float lsum = 0.f;
#pragma unroll
    for (int nj = 0; nj < 8; ++nj) {
      float r = cs.H[(n0 + nj) * XS_ + lane];
      lsum += r;
      h2out[((size_t)bs * 32 + n0 + nj) * 64 + lane] = r;
    }
    __syncthreads();                                 // BAR D (scratch free for psum)
    cs.scratch[lane * 5 + g2] = lsum;
    __syncthreads();                                 // BAR E
    if (tid < 64) {
      float v = (cs.scratch[tid * 5 + 0] + cs.scratch[tid * 5 + 1]) +
                (cs.scratch[tid * 5 + 2] + cs.scratch[tid * 5 + 3]);
      partials[(size_t)bs * 64 + tid] = v;
    }
  }

  // ---- phase B epilogue: publish done, then join the final phase ----
  __threadfence();
  __syncthreads();                   // all chunk work + LDS use complete
  if (t == 0)
    __hip_atomic_fetch_add(&prog[16], 1u, __ATOMIC_RELEASE, __HIP_MEMORY_SCOPE_AGENT);
  final_phase(smu.fin, t, blockIdx.x, prog, h2out, sig, ew, es, eb, et, outf);
}

// ---------------- K4: mean + ECA conv + sigmoid (fallback paths) -------------
__global__ __launch_bounds__(256) void k_eca(const float* __restrict__ partials,
                                             const float* __restrict__ ecak,
                                             float* __restrict__ sig) {
  __shared__ float red[64 * 5];
  __shared__ float yy[66];
  int b = blockIdx.x, t = threadIdx.x;
  int c = t & 63, sg = t >> 6;
  float acc = 0.f;
  for (int s = sg; s < S_; s += 4) acc += partials[((size_t)b * S_ + s) * 64 + c];
  red[c * 5 + sg] = acc;
  __syncthreads();
  if (t < 64) {
    float v = (red[t * 5 + 0] + red[t * 5 + 1]) + (red[t * 5 + 2] + red[t * 5 + 3]);
    yy[t + 1] = v * (1.f / 32768.f);
  }
  if (t == 64) { yy[0] = 0.f; yy[65] = 0.f; }
  __syncthreads();
  if (t < 64) {
    float gv = ecak[0] * yy[t] + ecak[1] * yy[t + 1] + ecak[2] * yy[t + 2];
    sig[b * 64 + t] = 1.f / (1.f + expf(-gv));
  }
}

// dual 64-row GEMM + max epilogue (fallback finals)
__device__ __forceinline__ void final_gemm(const float* __restrict__ WA,
                                           const float* __restrict__ WB,
                                           const float* __restrict__ X2,
                                           const float* __restrict__ esf,
                                           const float* __restrict__ bbf,
                                           float* __restrict__ zred,
                                           float* __restrict__ outf,
                                           int b, int s, int t) {
  int lane = t & 63, g = t >> 6, n0 = g * 8;
  float aA[8] = {0,0,0,0,0,0,0,0}, aB[8] = {0,0,0,0,0,0,0,0};
#pragma unroll
  for (int k4 = 0; k4 < 16; ++k4) {
    float4 wqA = *(const float4*)&WA[lane * XS_ + k4 * 4];
    float4 wqB = *(const float4*)&WB[lane * XS_ + k4 * 4];
#pragma unroll
    for (int nj = 0; nj < 8; ++nj) {
      float4 xq = *(const float4*)&X2[(n0 + nj) * XS_ + k4 * 4];
      aA[nj] += wqA.x * xq.x; aA[nj] += wqA.y * xq.y;
      aA[nj] += wqA.z * xq.z; aA[nj] += wqA.w * xq.w;
      aB[nj] += wqB.x * xq.x; aB[nj] += wqB.y * xq.y;
      aB[nj] += wqB.z * xq.z; aB[nj] += wqB.w * xq.w;
    }
  }
  float mA = aA[0], mB = aB[0];
#pragma unroll
  for (int j = 1; j < 8; ++j) { mA = fmaxf(mA, aA[j]); mB = fmaxf(mB, aB[j]); }
  zred[lane * 5 + g]        = esf[lane] * mA + bbf[lane];
  zred[(lane + 64) * 5 + g] = esf[lane + 64] * mB + bbf[lane + 64];
  __syncthreads();
  if (t < 128) {
    float m = fmaxf(fmaxf(zred[t * 5 + 0], zred[t * 5 + 1]),
                    fmaxf(zred[t * 5 + 2], zred[t * 5 + 3]));
    outf[((size_t)b * 128 + t) * S_ + s] = nanguard(m);
  }
}

// ---------------- K5b: recompute final (fallback) ----------------
template<bool USE_PTST>
__global__ __launch_bounds__(256) void k_final_rec(
    const float4* __restrict__ xyzt, const float* __restrict__ ptst,
    const float* __restrict__ points,
    const float4* __restrict__ nxf, const int* __restrict__ ballidx,
    const float* w0, const float* b0, const float* s0, const float* t0,
    const float* w1, const float* b1, const float* s1, const float* t1,
    const float* w2, const float* b2, const float* s2, const float* t2,
    const float* m0w, const float* m0b, const float* m0s, const float* m0t,
    const float* m1w, const float* m1b, const float* m1s, const float* m1t,
    const float* __restrict__ sig,
    const float* ew, const float* eb, const float* es, const float* et,
    float* __restrict__ outf) {
  __shared__ ChainSm sm;
  __shared__ float Wb2[64 * XS_];
  __shared__ float esf2[128], bbf2[128], sigl2[64];
  __shared__ float zred[128 * 5];
  int t = threadIdx.x, bs = blockIdx.x;
  int b = bs >> 10, s = bs & 1023;
  int lane = t & 63, g = t >> 6, n0 = g * 8;

  chain_tile<USE_PTST>(sm, b, s, bs, xyzt, ptst, points, nxf, ballidx,
                       w0, b0, s0, t0, w1, b1, s1, t1, w2, b2, s2, t2,
                       m0w, m0b, m0s, m0t, m1w, m1b, m1s, m1t);

  __syncthreads();
  stage_w64(sm.Wbuf, ew, t);
  stage_w64(Wb2, ew + 64 * 64, t);
  if (t < 128) {
    float v = es[t]; esf2[t] = v; bbf2[t] = v * eb[t] + et[t];
  }
  if (t < 64) sigl2[t] = sig[b * 64 + t];
  __syncthreads();
  {
#pragma unroll
    for (int nj = 0; nj < 8; ++nj)
      sm.X[(n0 + nj) * XS_ + lane] = sigl2[lane] * sm.H[(n0 + nj) * XS_ + lane];
  }
  final_gemm(sm.Wbuf, Wb2, sm.X, esf2, bbf2, zred, outf, b, s, t);
}

extern "C" void kernel_launch(void* const* d_in, const int* in_sizes, int n_in,
                              void* d_out, int out_size, void* d_ws, size_t ws_size,
                              hipStream_t stream) {
  const float* xyz    = (const float*)d_in[0];
  const float* points = (const float*)d_in[1];
  const float* w0 = (const float*)d_in[2],  *b0 = (const float*)d_in[3],  *s0 = (const float*)d_in[4],  *t0 = (const float*)d_in[5];
  const float* w1 = (const float*)d_in[6],  *b1 = (const float*)d_in[7],  *s1 = (const float*)d_in[8],  *t1 = (const float*)d_in[9];
  const float* w2 = (const float*)d_in[10], *b2 = (const float*)d_in[11], *s2 = (const float*)d_in[12], *t2 = (const float*)d_in[13];
  const float* m0w = (const float*)d_in[14], *m0b = (const float*)d_in[15], *m0s = (const float*)d_in[16], *m0t = (const float*)d_in[17];
  const float* m1w = (const float*)d_in[18], *m1b = (const float*)d_in[19], *m1s = (const float*)d_in[20], *m1t = (const float*)d_in[21];
  const float* ecak = (const float*)d_in[22];
  const float* ew = (const float*)d_in[23], *eb = (const float*)d_in[24], *es = (const float*)d_in[25], *et = (const float*)d_in[26];

  // ---- tiered workspace layout ----
  const size_t OFF_XYZT = 0;                 //  2,097,152 (B,N,4) f32
  const size_t OFF_NXF  = 2097152;           //    262,144 (B,S,4) f32
  const size_t OFF_BIDX = 2359296;           //  2,097,152 (B,S,32) i32 (fused: prog[18] lives here)
  const size_t OFF_PART = 4456448;           //  4,194,304 (B,S,64) f32
  const size_t OFF_SIG  = 8650752;           //      4,096 (B,64) f32
  const size_t OFF_PTST = 8654848;           // 33,554,432 (B,N,64) f32
  const size_t OFF_H2   = 42209280;          // 134,217,728 (B,S,32,64) f32
  const size_t NEED_PTST = OFF_H2;           // 42,209,280
  const size_t NEED_H2   = 176427008;

  const bool use_ptst = ws_size >= NEED_PTST;
  const bool use_h2   = ws_size >= NEED_H2;

  char* ws = (char*)d_ws;
  float4* xyzt    = (float4*)(ws + OFF_XYZT);
  float4* nxf     = (float4*)(ws + OFF_NXF);
  int*    ballidx = (int*)   (ws + OFF_BIDX);
  u32*    prog    = (u32*)   (ws + OFF_BIDX);   // shared region; exclusive per path
  float*  partials= (float*) (ws + OFF_PART);
  float*  sig     = (float*) (ws + OFF_SIG);
  float*  ptst    = (float*) (ws + OFF_PTST);
  float*  h2      = (float*) (ws + OFF_H2);

  float* out_xyz  = (float*)d_out;                          // (B,3,S) f32
  float* out_feat = (float*)d_out + (size_t)B_ * 3 * S_;    // (B,128,S) f32

  k_xyzt<<<dim3(N_ / 256, B_), 256, 0, stream>>>(xyz, xyzt, prog);
  if (use_ptst)
    k_ptst<<<dim3(N_ / 64, B_), 256, 0, stream>>>(points, ptst);

  if (use_h2) {
    // single fused kernel: fps + ball + chain + eca + final (no tail dispatches)
    k_fused<<<B_ + NWORK_, 1024, 0, stream>>>(xyzt, ptst, nxf, out_xyz, prog,
        w0, b0, s0, t0, w1, b1, s1, t1, w2, b2, s2, t2,
        m0w, m0b, m0s, m0t, m1w, m1b, m1s, m1t, h2, partials,
        ecak, ew, eb, es, et, sig, out_feat);
  } else if (use_ptst) {
    k_fps <<<B_, 1024, 0, stream>>>(xyzt, nxf, out_xyz);
    k_ball<<<(B_ * S_) / 4, 256, 0, stream>>>(xyzt, nxf, ballidx);
    k_chain<true, false><<<B_ * S_, 256, 0, stream>>>(xyzt, ptst, points, nxf, ballidx,
        w0, b0, s0, t0, w1, b1, s1, t1, w2, b2, s2, t2,
        m0w, m0b, m0s, m0t, m1w, m1b, m1s, m1t, h2, partials);
    k_eca<<<B_, 256, 0, stream>>>(partials, ecak, sig);
    k_final_rec<true><<<B_ * S_, 256, 0, stream>>>(xyzt, ptst, points, nxf, ballidx,
        w0, b0, s0, t0, w1, b1, s1, t1, w2, b2, s2, t2,
        m0w, m0b, m0s, m0t, m1w, m1b, m1s, m1t, sig, ew, eb, es, et, out_feat);
  } else {
    k_fps <<<B_, 1024, 0, stream>>>(xyzt, nxf, out_xyz);
    k_ball<<<(B_ * S_) / 4, 256, 0, stream>>>(xyzt, nxf, ballidx);
    k_chain<false, false><<<B_ * S_, 256, 0, stream>>>(xyzt, ptst, points, nxf, ballidx,
        w0, b0, s0, t0, w1, b1, s1, t1, w2, b2, s2, t2,
        m0w, m0b, m0s, m0t, m1w, m1b, m1s, m1t, h2, partials);
    k_eca<<<B_, 256, 0, stream>>>(partials, ecak, sig);
    k_final_rec<false><<<B_ * S_, 256, 0, stream>>>(xyzt, ptst, points, nxf, ballidx,
        w0, b0, s0, t0, w1, b1, s1, t1, w2, b2, s2, t2,
        m0w, m0b, m0s, m0t, m1w, m1b, m1s, m1t, sig, ew, eb, es, et, out_feat);
  }
}

// Round 10
// 1329.978 us; speedup vs baseline: 1.7295x; 1.7295x over previous
//
#include <hip/hip_runtime.h>

typedef unsigned int   u32;
typedef unsigned long long u64;
typedef float pkf2 __attribute__((ext_vector_type(2)));

#define B_  16
#define N_  8192
#define S_  1024
#define NS_ 32
#define XS_ 68   // [n][c] LDS row stride in floats (quad stride 17)
#define NWORK_ 240
#define NCHUNK_ 4096   // 1024 s-values x 4 b-groups; each chunk = 4 tiles (one per subgroup)

__device__ __forceinline__ float nanguard(float v) {
  u32 x = __float_as_uint(v);
  if ((x & 0x7F80u) == 0x7F80u) x ^= 0x0080u;
  return __uint_as_float(x);
}

// wave64 max via DPP (rocPRIM pattern)
__device__ __forceinline__ float wave_max_nonneg(float v) {
  int x = __float_as_int(v);
#define DPP_STEP(ctrl) \
  x = __float_as_int(fmaxf(__int_as_float(x), \
      __int_as_float(__builtin_amdgcn_update_dpp(0, x, (ctrl), 0xf, 0xf, true))))
  DPP_STEP(0x111);  // row_shr:1
  DPP_STEP(0x112);  // row_shr:2
  DPP_STEP(0x114);  // row_shr:4
  DPP_STEP(0x118);  // row_shr:8
  DPP_STEP(0x142);  // row_bcast15
  DPP_STEP(0x143);  // row_bcast31
#undef DPP_STEP
  return __int_as_float(__builtin_amdgcn_readlane(x, 63));
}

// ---------------- K0a: xyz (B,3,N) -> (B,N,4) f32 (+ zero sync counters) -----
// prog[0..15] = per-batch fps progress; prog[16] = worker-done; prog[17] = sig-done.
__global__ __launch_bounds__(256) void k_xyzt(const float* __restrict__ xyz, float4* __restrict__ xyzt,
                                              u32* __restrict__ prog) {
  if (blockIdx.x == 0 && blockIdx.y == 0 && threadIdx.x < 18) prog[threadIdx.x] = 0u;
  int b = blockIdx.y;
  int i = blockIdx.x * 256 + threadIdx.x;
  const float* p = xyz + (size_t)b * 3 * N_;
  xyzt[(size_t)b * N_ + i] = make_float4(p[i], p[N_ + i], p[2 * N_ + i], 0.f);
}

// ---------------- K0b: points (B,64,N) -> (B,N,64) f32 ----------------
__global__ __launch_bounds__(256) void k_ptst(const float* __restrict__ pts, float* __restrict__ ptst) {
  __shared__ float tile[64][65];
  int b = blockIdx.y, n0 = blockIdx.x * 64, t = threadIdx.x;
  {
    int c = t >> 2, j0 = (t & 3) * 16;
    const float4* src = (const float4*)(pts + (size_t)b * 64 * N_ + (size_t)c * N_ + n0 + j0);
#pragma unroll
    for (int q = 0; q < 4; ++q) {
      float4 a = src[q];
      tile[c][j0 + 4*q + 0] = a.x; tile[c][j0 + 4*q + 1] = a.y;
      tile[c][j0 + 4*q + 2] = a.z; tile[c][j0 + 4*q + 3] = a.w;
    }
  }
  __syncthreads();
  {
    int n = t >> 2, c0 = (t & 3) * 16;
    float4* dv = (float4*)(ptst + ((size_t)b * N_ + n0 + n) * 64 + c0);
#pragma unroll
    for (int q = 0; q < 4; ++q)
      dv[q] = make_float4(tile[c0 + 4*q + 0][n], tile[c0 + 4*q + 1][n],
                          tile[c0 + 4*q + 2][n], tile[c0 + 4*q + 3][n]);
  }
}

// ---------------- fallback K1: furthest point sampling (r12 verbatim) --------
__global__ __launch_bounds__(1024)
__attribute__((amdgpu_waves_per_eu(4, 4)))
void k_fps(const float4* __restrict__ xyzt,
           float4* __restrict__ nxf,
           float* __restrict__ out_xyz) {
#pragma clang fp contract(off)
  __shared__ float4 ldsp[N_];
  __shared__ u64 slot[4];
  __shared__ int win_hist[S_];
  int b = blockIdx.x, t = threadIdx.x;
  const float4* p4 = xyzt + (size_t)b * N_;
  const float4* pp8 = p4 + t * 8;

  float4 q0 = pp8[0], q1 = pp8[1], q2 = pp8[2], q3 = pp8[3];
  float4 q4 = pp8[4], q5 = pp8[5], q6 = pp8[6], q7 = pp8[7];
  ldsp[t * 8 + 0] = q0; ldsp[t * 8 + 1] = q1; ldsp[t * 8 + 2] = q2; ldsp[t * 8 + 3] = q3;
  ldsp[t * 8 + 4] = q4; ldsp[t * 8 + 5] = q5; ldsp[t * 8 + 6] = q6; ldsp[t * 8 + 7] = q7;

#define DECLPAIR(P, A, B) \
  pkf2 px##P = {q##A.x, q##B.x}; pkf2 py##P = {q##A.y, q##B.y}; \
  pkf2 pz##P = {q##A.z, q##B.z}; pkf2 dm##P = {1e10f, 1e10f};
  DECLPAIR(01, 0, 1) DECLPAIR(23, 2, 3) DECLPAIR(45, 4, 5) DECLPAIR(67, 6, 7)
#undef DECLPAIR
#define PIN(P) asm volatile("" : "+v"(px##P), "+v"(py##P), "+v"(pz##P));
  PIN(01) PIN(23) PIN(45) PIN(67)
#undef PIN

  if (t == 0) {
    slot[0] = 8191ull;
    slot[1] = 0; slot[2] = 0; slot[3] = 0;
    win_hist[0] = 0;
  }
  __syncthreads();
  int lane = t & 63;
  for (int it = 1; it < S_; ++it) {
    u64 w = slot[(it - 1) & 3];
    int widx = 8191 - (int)(w & 0xFFFFFFFFull);
    if (t == 0) { win_hist[it - 1] = widx; slot[(it + 1) & 3] = 0; }
    float4 c = ldsp[widx & (N_ - 1)];
    pkf2 cx2 = {c.x, c.x}, cy2 = {c.y, c.y}, cz2 = {c.z, c.z};
#define UPDP(P) { \
    pkf2 dx = px##P - cx2; pkf2 dy = py##P - cy2; pkf2 dz = pz##P - cz2; \
    pkf2 xx = dx * dx; pkf2 yy = dy * dy; pkf2 zz = dz * dz; \
    pkf2 ss = xx + yy; pkf2 dd = ss + zz; \
    dm##P.x = fminf(dm##P.x, dd.x); dm##P.y = fminf(dm##P.y, dd.y); }
    UPDP(01) UPDP(23) UPDP(45) UPDP(67)
#undef UPDP
    float e0 = dm01.x, e1 = dm01.y, e2 = dm23.x, e3 = dm23.y;
    float e4 = dm45.x, e5 = dm45.y, e6 = dm67.x, e7 = dm67.y;
    float va0 = e1 > e0 ? e1 : e0; int ia0 = e1 > e0 ? 1 : 0;
    float va1 = e3 > e2 ? e3 : e2; int ia1 = e3 > e2 ? 3 : 2;
    float va2 = e5 > e4 ? e5 : e4; int ia2 = e5 > e4 ? 5 : 4;
    float va3 = e7 > e6 ? e7 : e6; int ia3 = e7 > e6 ? 7 : 6;
    float vb0 = va1 > va0 ? va1 : va0; int ib0 = va1 > va0 ? ia1 : ia0;
    float vb1 = va3 > va2 ? va3 : va2; int ib1 = va3 > va2 ? ia3 : ia2;
    float bv = vb1 > vb0 ? vb1 : vb0;  int bk = vb1 > vb0 ? ib1 : ib0;
    int bi = t * 8 + bk;
    float wm = wave_max_nonneg(bv);
    u64 msk = __ballot(bv == wm);
    int wl = __ffsll((long long)msk) - 1;
    int wbi = __builtin_amdgcn_readlane(bi, wl);
    if (lane == 0)
      atomicMax(&slot[it & 3],
                ((u64)__float_as_uint(wm) << 32) | (u64)(u32)(8191 - wbi));
    __syncthreads();
  }
  if (t == 0)
    win_hist[S_ - 1] = 8191 - (int)(slot[(S_ - 1) & 3] & 0xFFFFFFFFull);
  __syncthreads();
  {
    int wi = win_hist[t] & (N_ - 1);
    float4 c = ldsp[wi];
    nxf[(size_t)b * S_ + t] = c;
    float* o = out_xyz + (size_t)b * 3 * S_;
    o[t] = nanguard(c.x); o[S_ + t] = nanguard(c.y); o[2 * S_ + t] = nanguard(c.z);
  }
}

// ---------------- fallback K2: ball query ----------------
__global__ __launch_bounds__(256) void k_ball(const float4* __restrict__ xyzt,
                                              const float4* __restrict__ nxf,
                                              int* __restrict__ ballidx) {
  int gw = blockIdx.x * 4 + (threadIdx.x >> 6);
  int lane = threadIdx.x & 63;
  int b = gw >> 10, s = gw & 1023;
  float4 c = nxf[(size_t)b * S_ + s];
  const float4* pts = xyzt + (size_t)b * N_;
  int* out = ballidx + (size_t)gw * NS_;
  int cnt = 0, first = 0;
  bool havefirst = false;
  for (int chunk = 0; chunk < N_; chunk += 64) {
    float4 p = pts[chunk + lane];
    float dx = p.x - c.x, dy = p.y - c.y, dz = p.z - c.z;
    float d2 = __fadd_rn(__fadd_rn(__fmul_rn(dx, dx), __fmul_rn(dy, dy)), __fmul_rn(dz, dz));
    bool v = d2 <= 0.04f;
    u64 m = __ballot(v);
    if (m) {
      int pos = cnt + __popcll(m & ((1ull << lane) - 1ull));
      if (v && pos < NS_) out[pos] = chunk + lane;
      if (!havefirst) { first = chunk + (__ffsll((long long)m) - 1); havefirst = true; }
      cnt += __popcll(m);
      if (cnt >= NS_) break;
    }
  }
  if (cnt < NS_) {
    for (int p = cnt + lane; p < NS_; p += 64) out[p] = first;
  }
}

// ---------------- chain machinery (fallback path, r10 verbatim) --------------
struct ChainSm {
  float Wbuf[64 * XS_];
  float W1f[64 * 9];
  float W0f[8 * 4];
  float s2f[64], sm0f[64], sm1f[64];
  float bb0[8];
  float bb1[64], bb2[64], bm0[64], bm1[64];
  float X[32 * XS_];
  float H[32 * XS_];
  float scratch[384];
  int   idx_s[NS_];
};

__device__ __forceinline__ void stage_w64(float* Wbuf, const float* w, int t) {
  int c = t >> 2, q = (t & 3) * 16;
  const float4* src = (const float4*)(w + c * 64 + q);
  float4* dst = (float4*)(Wbuf + c * XS_ + q);
  dst[0] = src[0]; dst[1] = src[1]; dst[2] = src[2]; dst[3] = src[3];
}

template<bool RELU>
__device__ __forceinline__ void gemm64(const float* __restrict__ Wbuf,
                                       const float* __restrict__ Xin,
                                       float* __restrict__ Yout,
                                       const float* __restrict__ scl,
                                       const float* __restrict__ bia,
                                       int lane, int n0) {
  float acc[8] = {0,0,0,0,0,0,0,0};
#pragma unroll
  for (int k4 = 0; k4 < 16; ++k4) {
    float4 wq = *(const float4*)&Wbuf[lane * XS_ + k4 * 4];
#pragma unroll
    for (int nj = 0; nj < 8; ++nj) {
      float4 xq = *(const float4*)&Xin[(n0 + nj) * XS_ + k4 * 4];
      acc[nj] += wq.x * xq.x; acc[nj] += wq.y * xq.y;
      acc[nj] += wq.z * xq.z; acc[nj] += wq.w * xq.w;
    }
  }
  float sc = scl[lane], bi = bia[lane];
#pragma unroll
  for (int nj = 0; nj < 8; ++nj) {
    float v = sc * acc[nj] + bi;
    Yout[(n0 + nj) * XS_ + lane] = RELU ? fmaxf(v, 0.f) : v;
  }
}

template<bool USE_PTST>
__device__ __forceinline__ void chain_tile(ChainSm& sm, int b, int s, int bs,
    const float4* xyzt, const float* ptst, const float* points,
    const float4* nxf, const int* ballidx,
    const float* w0, const float* b0, const float* s0, const float* t0,
    const float* w1, const float* b1, const float* s1, const float* t1,
    const float* w2, const float* b2, const float* s2, const float* t2,
    const float* m0w, const float* m0b, const float* m0s, const float* m0t,
    const float* m1w, const float* m1b, const float* m1s, const float* m1t) {
  int t = threadIdx.x, lane = t & 63, g = t >> 6, n0 = g * 8;

  stage_w64(sm.Wbuf, w2, t);
  if (t < 64) {
    float v2 = s2[t];  sm.s2f[t] = v2;  sm.bb2[t] = v2 * b2[t] + t2[t];
    float vm0 = m0s[t]; sm.sm0f[t] = vm0; sm.bm0[t] = vm0 * m0b[t] + m0t[t];
    float vm1 = m1s[t]; sm.sm1f[t] = vm1; sm.bm1[t] = vm1 * m1b[t] + m1t[t];
    float v1 = s1[t];
#pragma unroll
    for (int k = 0; k < 8; ++k) sm.W1f[t * 9 + k] = v1 * w1[t * 8 + k];
    sm.bb1[t] = v1 * b1[t] + t1[t];
  }
  if (t < 8) {
    float v0 = s0[t];
#pragma unroll
    for (int k = 0; k < 3; ++k) sm.W0f[t * 4 + k] = v0 * w0[t * 3 + k];
    sm.bb0[t] = v0 * b0[t] + t0[t];
  }
  if (t < NS_) sm.idx_s[t] = ballidx[(size_t)bs * NS_ + t] & (N_ - 1);
  __syncthreads();                                   // B1

  {
    int n = t >> 3, c8 = (t & 7) * 8;
    int pi = sm.idx_s[n];
    if (USE_PTST) {
      const float4* v = (const float4*)(ptst + ((size_t)b * N_ + pi) * 64 + c8);
      float4* xr = (float4*)&sm.X[n * XS_ + c8];
      xr[0] = v[0]; xr[1] = v[1];
    } else {
      const float* pp = points + (size_t)b * 64 * N_ + (size_t)c8 * N_ + pi;
#pragma unroll
      for (int j = 0; j < 8; ++j) sm.X[n * XS_ + c8 + j] = pp[(size_t)j * N_];
    }
  }
  if (t < NS_) {
    float4 p = xyzt[(size_t)b * N_ + sm.idx_s[t]];
    float4 cc = nxf[(size_t)b * S_ + s];
    float* gx = &sm.scratch[256 + t * 4];
    gx[0] = p.x - cc.x; gx[1] = p.y - cc.y; gx[2] = p.z - cc.z;
  }
  __syncthreads();                                   // B2

  {
    int n = t >> 3, cc = t & 7;
    const float* gx = &sm.scratch[256 + n * 4];
    float a = sm.bb0[cc];
    a += sm.W0f[cc * 4 + 0] * gx[0];
    a += sm.W0f[cc * 4 + 1] * gx[1];
    a += sm.W0f[cc * 4 + 2] * gx[2];
    sm.scratch[n * 8 + cc] = fmaxf(a, 0.f);
  }
  {
#pragma unroll
    for (int nj = 0; nj < 8; ++nj) {
      float a = sm.bb1[lane];
      const float* p8 = &sm.scratch[(n0 + nj) * 8];
#pragma unroll
      for (int k = 0; k < 8; ++k) a += sm.W1f[lane * 9 + k] * p8[k];
      sm.X[(n0 + nj) * XS_ + lane] += a;
    }
  }
  gemm64<false>(sm.Wbuf, sm.X, sm.H, sm.s2f, sm.bb2, lane, n0);
  __syncthreads();                                   // B3
  stage_w64(sm.Wbuf, m0w, t);
  __syncthreads();                                   // B4
  gemm64<true>(sm.Wbuf, sm.H, sm.X, sm.sm0f, sm.bm0, lane, n0);
  __syncthreads();                                   // B5
  stage_w64(sm.Wbuf, m1w, t);
  __syncthreads();                                   // B6
  gemm64<true>(sm.Wbuf, sm.X, sm.H, sm.sm1f, sm.bm1, lane, n0);
}

// ---------------- fallback K3: chain pass ----------------
template<bool USE_PTST, bool WRITE_H2>
__global__ __launch_bounds__(256) void k_chain(
    const float4* __restrict__ xyzt, const float* __restrict__ ptst,
    const float* __restrict__ points,
    const float4* __restrict__ nxf, const int* __restrict__ ballidx,
    const float* w0, const float* b0, const float* s0, const float* t0,
    const float* w1, const float* b1, const float* s1, const float* t1,
    const float* w2, const float* b2, const float* s2, const float* t2,
    const float* m0w, const float* m0b, const float* m0s, const float* m0t,
    const float* m1w, const float* m1b, const float* m1s, const float* m1t,
    float* __restrict__ h2out, float* __restrict__ partials) {
  __shared__ ChainSm sm;
  int t = threadIdx.x, bs = blockIdx.x;
  int b = bs >> 10, s = bs & 1023;
  int lane = t & 63, g = t >> 6, n0 = g * 8;

  chain_tile<USE_PTST>(sm, b, s, bs, xyzt, ptst, points, nxf, ballidx,
                       w0, b0, s0, t0, w1, b1, s1, t1, w2, b2, s2, t2,
                       m0w, m0b, m0s, m0t, m1w, m1b, m1s, m1t);

  float* psum = sm.scratch;
  float lsum = 0.f;
#pragma unroll
  for (int nj = 0; nj < 8; ++nj) {
    float r = sm.H[(n0 + nj) * XS_ + lane];
    lsum += r;
    if (WRITE_H2)
      h2out[((size_t)bs * 32 + n0 + nj) * 64 + lane] = r;
  }
  psum[lane * 5 + g] = lsum;
  __syncthreads();                                   // B7
  if (t < 64) {
    float v = (psum[t * 5 + 0] + psum[t * 5 + 1]) + (psum[t * 5 + 2] + psum[t * 5 + 3]);
    partials[(size_t)bs * 64 + t] = v;
  }
}

// ---------------- fully-fused fps + ball + chain + eca + final ---------------
// r8/r9 post-mortem: scratch traffic (FETCH 1.9GB/WRITE 2.3GB) was INVARIANT
// to phase-D acc blocking size -> spill cause is the fully-unrolled it x half
// x rh x k4 straight-line code (scheduler interleaves loads across unrolled
// tile iterations -> liveness explosion past the 64-reg allocation). Fix:
// unroll discipline -- #pragma unroll 1 on it/half/rh, unroll 2 on k4. Live
// set ~50 regs, bounded per-iteration code, no cross-tile interleave.
struct ChainSub {
  float X[32 * XS_];
  float H[32 * XS_];
  float scratch[384];
  int   idx_s[NS_];
};
struct WkSm {
  float Wc2[64 * XS_];
  float Wm0[64 * XS_];
  float Wm1[64 * XS_];
  float W1f[64 * 9];
  float W0f[8 * 4];
  float s2f[64], sm0f[64], sm1f[64];
  float bb0[8];
  float bb1[64], bb2[64], bm0[64], bm1[64];
  ChainSub sub[4];
};
struct FpsSm {
  float4 ldsp[N_];
  u64 slot[4];
  int win_hist[S_];
};
struct FinSm {
  float Wh[128 * XS_];
  float esf[128], bbf[128];
  float sigl[64];
  float red[64 * 5];
  float yy[66];
};
union FusedSm { FpsSm f; WkSm w; FinSm fin; };
static_assert(sizeof(FusedSm) <= 160 * 1024, "LDS overflow");

__device__ __forceinline__ void final_phase(FinSm& fin, int t, int blkid, u32* prog,
    const float* __restrict__ h2, const float* __restrict__ sig,
    const float* __restrict__ ew, const float* __restrict__ es,
    const float* __restrict__ eb, const float* __restrict__ et,
    float* __restrict__ outf) {
  // stage ew/esf/bbf while (possibly) waiting for sig
  if (t < 256) {
    int c2 = t >> 1, h = (t & 1) * 32;
    const float4* src = (const float4*)(ew + c2 * 64 + h);
    float4* dst = (float4*)(fin.Wh + c2 * XS_ + h);
#pragma unroll
    for (int j = 0; j < 8; ++j) dst[j] = src[j];
  }
  if (t < 128) { float v = es[t]; fin.esf[t] = v; fin.bbf[t] = v * eb[t] + et[t]; }
  if (t == 0) {
    while (__hip_atomic_load(&prog[17], __ATOMIC_RELAXED, __HIP_MEMORY_SCOPE_AGENT) < 16u)
      __builtin_amdgcn_s_sleep(8);
    (void)__hip_atomic_load(&prog[17], __ATOMIC_ACQUIRE, __HIP_MEMORY_SCOPE_AGENT);
  }
  __syncthreads();
  if (t < 64) fin.sigl[t] = sig[(blkid >> 4) * 64 + t];   // block-uniform b
  __syncthreads();

  int wv = t >> 6, lane = t & 63;
  int cg = lane & 15, rg = lane >> 4;
#pragma unroll 1
  for (int it = 0; it < 4; ++it) {
    int bs = blkid * 64 + it * 16 + wv;
    int b = bs >> 10, s = bs & 1023;
    const float* hsrc = h2 + (size_t)bs * 2048;
#pragma unroll 1
    for (int half = 0; half < 2; ++half) {
      float pm0 = -3.4e38f, pm1 = -3.4e38f, pm2 = -3.4e38f, pm3 = -3.4e38f;
#pragma unroll 1
      for (int rh = 0; rh < 2; ++rh) {
        float acc[4][4];
#pragma unroll
        for (int i = 0; i < 4; ++i)
#pragma unroll
          for (int j = 0; j < 4; ++j) acc[i][j] = 0.f;
#pragma unroll 2
        for (int k4 = 0; k4 < 16; ++k4) {
          float4 sgl = *(const float4*)&fin.sigl[k4 * 4];   // LDS broadcast
          float4 xq[4];
#pragma unroll
          for (int j = 0; j < 4; ++j) {
            float4 v = *(const float4*)&hsrc[(size_t)(rg + 4 * (rh * 4 + j)) * 64 + k4 * 4];
            v.x *= sgl.x; v.y *= sgl.y; v.z *= sgl.z; v.w *= sgl.w;
            xq[j] = v;
          }
#pragma unroll
          for (int i = 0; i < 4; ++i) {
            float4 wq = *(const float4*)&fin.Wh[(half * 64 + cg + 16 * i) * XS_ + k4 * 4];
#pragma unroll
            for (int j = 0; j < 4; ++j) {
              acc[i][j] += wq.x * xq[j].x; acc[i][j] += wq.y * xq[j].y;
              acc[i][j] += wq.z * xq[j].z; acc[i][j] += wq.w * xq[j].w;
            }
          }
        }
#define RED(i, mv) { \
        float a0 = fmaxf(fmaxf(acc[i][0], acc[i][1]), fmaxf(acc[i][2], acc[i][3])); \
        mv = fmaxf(mv, a0); }
        RED(0, pm0) RED(1, pm1) RED(2, pm2) RED(3, pm3)
#undef RED
      }
      // cross-row-group max (lanes cg, cg+16, cg+32, cg+48 hold partials)
#define SHR(mv) { mv = fmaxf(mv, __shfl_xor(mv, 16)); mv = fmaxf(mv, __shfl_xor(mv, 32)); }
      SHR(pm0) SHR(pm1) SHR(pm2) SHR(pm3)
#undef SHR
      float msel = rg == 0 ? pm0 : rg == 1 ? pm1 : rg == 2 ? pm2 : pm3;
      int c = half * 64 + cg + 16 * rg;
      outf[((size_t)b * 128 + c) * S_ + s] = nanguard(fin.esf[c] * msel + fin.bbf[c]);
    }
  }
}

__global__ __launch_bounds__(1024)
__attribute__((amdgpu_waves_per_eu(4, 4)))
void k_fused(const float4* __restrict__ xyzt, const float* __restrict__ ptst,
             float4* __restrict__ nxf, float* __restrict__ out_xyz,
             u32* __restrict__ prog,
             const float* w0, const float* b0, const float* s0, const float* t0,
             const float* w1, const float* b1, const float* s1, const float* t1,
             const float* w2, const float* b2, const float* s2, const float* t2,
             const float* m0w, const float* m0b, const float* m0s, const float* m0t,
             const float* m1w, const float* m1b, const float* m1s, const float* m1t,
             float* __restrict__ h2out, float* __restrict__ partials,
             const float* __restrict__ ecak,
             const float* __restrict__ ew, const float* __restrict__ eb,
             const float* __restrict__ es, const float* __restrict__ et,
             float* __restrict__ sig, float* __restrict__ outf) {
  __shared__ FusedSm smu;
  int t = threadIdx.x;

  if (blockIdx.x < B_) {
    // ================= fps producer =================
#pragma clang fp contract(off)
    FpsSm& fs = smu.f;
    int b = blockIdx.x;
    const float4* p4 = xyzt + (size_t)b * N_;
    const float4* pp8 = p4 + t * 8;

    float4 q0 = pp8[0], q1 = pp8[1], q2 = pp8[2], q3 = pp8[3];
    float4 q4 = pp8[4], q5 = pp8[5], q6 = pp8[6], q7 = pp8[7];
    fs.ldsp[t * 8 + 0] = q0; fs.ldsp[t * 8 + 1] = q1; fs.ldsp[t * 8 + 2] = q2; fs.ldsp[t * 8 + 3] = q3;
    fs.ldsp[t * 8 + 4] = q4; fs.ldsp[t * 8 + 5] = q5; fs.ldsp[t * 8 + 6] = q6; fs.ldsp[t * 8 + 7] = q7;

#define DECLPAIR(P, A, B) \
    pkf2 px##P = {q##A.x, q##B.x}; pkf2 py##P = {q##A.y, q##B.y}; \
    pkf2 pz##P = {q##A.z, q##B.z}; pkf2 dm##P = {1e10f, 1e10f};
    DECLPAIR(01, 0, 1) DECLPAIR(23, 2, 3) DECLPAIR(45, 4, 5) DECLPAIR(67, 6, 7)
#undef DECLPAIR
#define PIN(P) asm volatile("" : "+v"(px##P), "+v"(py##P), "+v"(pz##P));
    PIN(01) PIN(23) PIN(45) PIN(67)
#undef PIN

    if (t == 0) {
      fs.slot[0] = 8191ull;
      fs.slot[1] = 0; fs.slot[2] = 0; fs.slot[3] = 0;
      fs.win_hist[0] = 0;
    }
    __syncthreads();
    int lane = t & 63;
    for (int it = 1; it < S_; ++it) {
      u64 w = fs.slot[(it - 1) & 3];
      int widx = 8191 - (int)(w & 0xFFFFFFFFull);
      float4 c = fs.ldsp[widx & (N_ - 1)];
      if (t == 0) {
        fs.win_hist[it - 1] = widx; fs.slot[(it + 1) & 3] = 0;
        if ((it & 15) == 0)
          __hip_atomic_store(&prog[b], (u32)(it - 1), __ATOMIC_RELEASE, __HIP_MEMORY_SCOPE_AGENT);
        nxf[(size_t)b * S_ + (it - 1)] = c;
      }
      pkf2 cx2 = {c.x, c.x}, cy2 = {c.y, c.y}, cz2 = {c.z, c.z};
#define UPDP(P) { \
      pkf2 dx = px##P - cx2; pkf2 dy = py##P - cy2; pkf2 dz = pz##P - cz2; \
      pkf2 xx = dx * dx; pkf2 yy = dy * dy; pkf2 zz = dz * dz; \
      pkf2 ss = xx + yy; pkf2 dd = ss + zz; \
      dm##P.x = fminf(dm##P.x, dd.x); dm##P.y = fminf(dm##P.y, dd.y); }
      UPDP(01) UPDP(23) UPDP(45) UPDP(67)
#undef UPDP
      float e0 = dm01.x, e1 = dm01.y, e2 = dm23.x, e3 = dm23.y;
      float e4 = dm45.x, e5 = dm45.y, e6 = dm67.x, e7 = dm67.y;
      float va0 = e1 > e0 ? e1 : e0; int ia0 = e1 > e0 ? 1 : 0;
      float va1 = e3 > e2 ? e3 : e2; int ia1 = e3 > e2 ? 3 : 2;
      float va2 = e5 > e4 ? e5 : e4; int ia2 = e5 > e4 ? 5 : 4;
      float va3 = e7 > e6 ? e7 : e6; int ia3 = e7 > e6 ? 7 : 6;
      float vb0 = va1 > va0 ? va1 : va0; int ib0 = va1 > va0 ? ia1 : ia0;
      float vb1 = va3 > va2 ? va3 : va2; int ib1 = va3 > va2 ? ia3 : ia2;
      float bv = vb1 > vb0 ? vb1 : vb0;  int bk = vb1 > vb0 ? ib1 : ib0;
      int bi = t * 8 + bk;
      float wm = wave_max_nonneg(bv);
      u64 msk = __ballot(bv == wm);
      int wl = __ffsll((long long)msk) - 1;
      int wbi = __builtin_amdgcn_readlane(bi, wl);
      if (lane == 0)
        atomicMax(&fs.slot[it & 3],
                  ((u64)__float_as_uint(wm) << 32) | (u64)(u32)(8191 - wbi));
      __syncthreads();
    }
    if (t == 0) {
      int wl_ = 8191 - (int)(fs.slot[(S_ - 1) & 3] & 0xFFFFFFFFull);
      fs.win_hist[S_ - 1] = wl_;
      float4 c = fs.ldsp[wl_ & (N_ - 1)];
      nxf[(size_t)b * S_ + (S_ - 1)] = c;
    }
    __syncthreads();
    {
      int wi = fs.win_hist[t] & (N_ - 1);
      float4 c = fs.ldsp[wi];
      float* o = out_xyz + (size_t)b * 3 * S_;
      o[t] = nanguard(c.x); o[S_ + t] = nanguard(c.y); o[2 * S_ + t] = nanguard(c.z);
    }
    if (t == 0)
      __hip_atomic_store(&prog[b], (u32)S_, __ATOMIC_RELEASE, __HIP_MEMORY_SCOPE_AGENT);

    // ---- phase C: eca for this block's b (exact k_eca replica, t<256) ----
    __syncthreads();                 // ldsp reads complete; FinSm overlay safe
    FinSm& fin = smu.fin;
    if (t == 0) {
      while (__hip_atomic_load(&prog[16], __ATOMIC_RELAXED, __HIP_MEMORY_SCOPE_AGENT) < (u32)NWORK_)
        __builtin_amdgcn_s_sleep(32);
      (void)__hip_atomic_load(&prog[16], __ATOMIC_ACQUIRE, __HIP_MEMORY_SCOPE_AGENT);
    }
    __syncthreads();
    if (t < 256) {
      int c = t & 63, sg = t >> 6;
      float acc = 0.f;
      for (int s2 = sg; s2 < S_; s2 += 4)
        acc += partials[((size_t)b * S_ + s2) * 64 + c];
      fin.red[c * 5 + sg] = acc;
    }
    __syncthreads();
    if (t < 64) {
      float v = (fin.red[t * 5 + 0] + fin.red[t * 5 + 1]) + (fin.red[t * 5 + 2] + fin.red[t * 5 + 3]);
      fin.yy[t + 1] = v * (1.f / 32768.f);
    }
    if (t == 64) { fin.yy[0] = 0.f; fin.yy[65] = 0.f; }
    __syncthreads();
    if (t < 64) {
      float gv = ecak[0] * fin.yy[t] + ecak[1] * fin.yy[t + 1] + ecak[2] * fin.yy[t + 2];
      sig[b * 64 + t] = 1.f / (1.f + expf(-gv));
    }
    __threadfence();
    __syncthreads();
    if (t == 0)
      __hip_atomic_fetch_add(&prog[17], 1u, __ATOMIC_RELEASE, __HIP_MEMORY_SCOPE_AGENT);
    final_phase(fin, t, blockIdx.x, prog, h2out, sig, ew, es, eb, et, outf);
    return;
  }

  // ================= worker =================
  WkSm& wk = smu.w;
  int w = blockIdx.x - B_;
  if (t < 256) {
    stage_w64(wk.Wc2, w2, t);
    stage_w64(wk.Wm0, m0w, t);
    stage_w64(wk.Wm1, m1w, t);
  }
  if (t < 64) {
    float v2 = s2[t];  wk.s2f[t] = v2;  wk.bb2[t] = v2 * b2[t] + t2[t];
    float vm0 = m0s[t]; wk.sm0f[t] = vm0; wk.bm0[t] = vm0 * m0b[t] + m0t[t];
    float vm1 = m1s[t]; wk.sm1f[t] = vm1; wk.bm1[t] = vm1 * m1b[t] + m1t[t];
    float v1 = s1[t];
#pragma unroll
    for (int k = 0; k < 8; ++k) wk.W1f[t * 9 + k] = v1 * w1[t * 8 + k];
    wk.bb1[t] = v1 * b1[t] + t1[t];
  }
  if (t < 8) {
    float v0 = s0[t];
#pragma unroll
    for (int k = 0; k < 3; ++k) wk.W0f[t * 4 + k] = v0 * w0[t * 3 + k];
    wk.bb0[t] = v0 * b0[t] + t0[t];
  }
  __syncthreads();

  int sg = t >> 8, tid = t & 255, lane = t & 63, g2 = (t >> 6) & 3, n0 = g2 * 8;
  ChainSub& cs = wk.sub[sg];

  for (int ck = w; ck < NCHUNK_; ck += NWORK_) {
    int s = ck >> 2, bg = ck & 3, b = bg * 4 + sg;
    if (t == 0) {
      int bbase = bg * 4;
#pragma unroll
      for (int j = 0; j < 4; ++j) {
        while (__hip_atomic_load(&prog[bbase + j], __ATOMIC_RELAXED, __HIP_MEMORY_SCOPE_AGENT) < (u32)(s + 1))
          __builtin_amdgcn_s_sleep(32);
      }
      (void)__hip_atomic_load(&prog[bbase], __ATOMIC_ACQUIRE, __HIP_MEMORY_SCOPE_AGENT);
    }
    __syncthreads();                                 // BAR A (data for s visible)

    float4 cc;
    if (g2 == 0) {
      cc = nxf[(size_t)b * S_ + s];
      const float4* pts = xyzt + (size_t)b * N_;
      int cnt = 0, first = 0;
      bool havefirst = false;
      for (int chunk = 0; chunk < N_; chunk += 64) {
        float4 p = pts[chunk + lane];
        float dx = p.x - cc.x, dy = p.y - cc.y, dz = p.z - cc.z;
        float d2 = __fadd_rn(__fadd_rn(__fmul_rn(dx, dx), __fmul_rn(dy, dy)), __fmul_rn(dz, dz));
        bool v = d2 <= 0.04f;
        u64 m = __ballot(v);
        if (m) {
          int pos = cnt + __popcll(m & ((1ull << lane) - 1ull));
          if (v && pos < NS_) cs.idx_s[pos] = chunk + lane;
          if (!havefirst) { first = chunk + (__ffsll((long long)m) - 1); havefirst = true; }
          cnt += __popcll(m);
          if (cnt >= NS_) break;
        }
      }
      if (cnt < NS_) {
        for (int p = cnt + lane; p < NS_; p += 64) cs.idx_s[p] = first;
      }
    }
    __syncthreads();                                 // BAR B (idx_s ready)

    {
      int n = tid >> 3, c8 = (tid & 7) * 8;
      int pi = cs.idx_s[n];
      const float4* v = (const float4*)(ptst + ((size_t)b * N_ + pi) * 64 + c8);
      float4* xr = (float4*)&cs.X[n * XS_ + c8];
      xr[0] = v[0]; xr[1] = v[1];
    }
    if (tid < NS_) {
      float4 p = xyzt[(size_t)b * N_ + cs.idx_s[tid]];
      float* gx = &cs.scratch[256 + tid * 4];
      gx[0] = p.x - cc.x; gx[1] = p.y - cc.y; gx[2] = p.z - cc.z;
    }
    __syncthreads();                                 // BAR C (GX cross-wave)

    {
      int n = tid >> 3, ch = tid & 7;
      const float* gx = &cs.scratch[256 + n * 4];
      float a = wk.bb0[ch];
      a += wk.W0f[ch * 4 + 0] * gx[0];
      a += wk.W0f[ch * 4 + 1] * gx[1];
      a += wk.W0f[ch * 4 + 2] * gx[2];
      cs.scratch[n * 8 + ch] = fmaxf(a, 0.f);
    }
    {
#pragma unroll
      for (int nj = 0; nj < 8; ++nj) {
        float a = wk.bb1[lane];
        const float* p8 = &cs.scratch[(n0 + nj) * 8];
#pragma unroll
        for (int k = 0; k < 8; ++k) a += wk.W1f[lane * 9 + k] * p8[k];
        cs.X[(n0 + nj) * XS_ + lane] += a;
      }
    }
    gemm64<false>(wk.Wc2, cs.X, cs.H, wk.s2f, wk.bb2, lane, n0);
    gemm64<true >(wk.Wm0, cs.H, cs.X, wk.sm0f, wk.bm0, lane, n0);
    gemm64<true >(wk.Wm1, cs.X, cs.H, wk.sm1f, wk.bm1, lane, n0);

    int bs = (b << 10) | s;
    float lsum = 0.f;
#pragma unroll
    for (int nj = 0; nj < 8; ++nj) {
      float r = cs.H[(n0 + nj) * XS_ + lane];
      lsum += r;
      h2out[((size_t)bs * 32 + n0 + nj) * 64 + lane] = r;
    }
    __syncthreads();                                 // BAR D (scratch free for psum)
    cs.scratch[lane * 5 + g2] = lsum;
    __syncthreads();                                 // BAR E
    if (tid < 64) {
      float v = (cs.scratch[tid * 5 + 0] + cs.scratch[tid * 5 + 1]) +
                (cs.scratch[tid * 5 + 2] + cs.scratch[tid * 5 + 3]);
      partials[(size_t)bs * 64 + tid] = v;
    }
  }

  // ---- phase B epilogue: publish done, then join the final phase ----
  __threadfence();
  __syncthreads();                   // all chunk work + LDS use complete
  if (t == 0)
    __hip_atomic_fetch_add(&prog[16], 1u, __ATOMIC_RELEASE, __HIP_MEMORY_SCOPE_AGENT);
  final_phase(smu.fin, t, blockIdx.x, prog, h2out, sig, ew, es, eb, et, outf);
}

// ---------------- K4: mean + ECA conv + sigmoid (fallback paths) -------------
__global__ __launch_bounds__(256) void k_eca(const float* __restrict__ partials,
                                             const float* __restrict__ ecak,
                                             float* __restrict__ sig) {
  __shared__ float red[64 * 5];
  __shared__ float yy[66];
  int b = blockIdx.x, t = threadIdx.x;
  int c = t & 63, sg = t >> 6;
  float acc = 0.f;
  for (int s = sg; s < S_; s += 4) acc += partials[((size_t)b * S_ + s) * 64 + c];
  red[c * 5 + sg] = acc;
  __syncthreads();
  if (t < 64) {
    float v = (red[t * 5 + 0] + red[t * 5 + 1]) + (red[t * 5 + 2] + red[t * 5 + 3]);
    yy[t + 1] = v * (1.f / 32768.f);
  }
  if (t == 64) { yy[0] = 0.f; yy[65] = 0.f; }
  __syncthreads();
  if (t < 64) {
    float gv = ecak[0] * yy[t] + ecak[1] * yy[t + 1] + ecak[2] * yy[t + 2];
    sig[b * 64 + t] = 1.f / (1.f + expf(-gv));
  }
}

// dual 64-row GEMM + max epilogue (fallback finals)
__device__ __forceinline__ void final_gemm(const float* __restrict__ WA,
                                           const float* __restrict__ WB,
                                           const float* __restrict__ X2,
                                           const float* __restrict__ esf,
                                           const float* __restrict__ bbf,
                                           float* __restrict__ zred,
                                           float* __restrict__ outf,
                                           int b, int s, int t) {
  int lane = t & 63, g = t >> 6, n0 = g * 8;
  float aA[8] = {0,0,0,0,0,0,0,0}, aB[8] = {0,0,0,0,0,0,0,0};
#pragma unroll
  for (int k4 = 0; k4 < 16; ++k4) {
    float4 wqA = *(const float4*)&WA[lane * XS_ + k4 * 4];
    float4 wqB = *(const float4*)&WB[lane * XS_ + k4 * 4];
#pragma unroll
    for (int nj = 0; nj < 8; ++nj) {
      float4 xq = *(const float4*)&X2[(n0 + nj) * XS_ + k4 * 4];
      aA[nj] += wqA.x * xq.x; aA[nj] += wqA.y * xq.y;
      aA[nj] += wqA.z * xq.z; aA[nj] += wqA.w * xq.w;
      aB[nj] += wqB.x * xq.x; aB[nj] += wqB.y * xq.y;
      aB[nj] += wqB.z * xq.z; aB[nj] += wqB.w * xq.w;
    }
  }
  float mA = aA[0], mB = aB[0];
#pragma unroll
  for (int j = 1; j < 8; ++j) { mA = fmaxf(mA, aA[j]); mB = fmaxf(mB, aB[j]); }
  zred[lane * 5 + g]        = esf[lane] * mA + bbf[lane];
  zred[(lane + 64) * 5 + g] = esf[lane + 64] * mB + bbf[lane + 64];
  __syncthreads();
  if (t < 128) {
    float m = fmaxf(fmaxf(zred[t * 5 + 0], zred[t * 5 + 1]),
                    fmaxf(zred[t * 5 + 2], zred[t * 5 + 3]));
    outf[((size_t)b * 128 + t) * S_ + s] = nanguard(m);
  }
}

// ---------------- K5b: recompute final (fallback) ----------------
template<bool USE_PTST>
__global__ __launch_bounds__(256) void k_final_rec(
    const float4* __restrict__ xyzt, const float* __restrict__ ptst,
    const float* __restrict__ points,
    const float4* __restrict__ nxf, const int* __restrict__ ballidx,
    const float* w0, const float* b0, const float* s0, const float* t0,
    const float* w1, const float* b1, const float* s1, const float* t1,
    const float* w2, const float* b2, const float* s2, const float* t2,
    const float* m0w, const float* m0b, const float* m0s, const float* m0t,
    const float* m1w, const float* m1b, const float* m1s, const float* m1t,
    const float* __restrict__ sig,
    const float* ew, const float* eb, const float* es, const float* et,
    float* __restrict__ outf) {
  __shared__ ChainSm sm;
  __shared__ float Wb2[64 * XS_];
  __shared__ float esf2[128], bbf2[128], sigl2[64];
  __shared__ float zred[128 * 5];
  int t = threadIdx.x, bs = blockIdx.x;
  int b = bs >> 10, s = bs & 1023;
  int lane = t & 63, g = t >> 6, n0 = g * 8;

  chain_tile<USE_PTST>(sm, b, s, bs, xyzt, ptst, points, nxf, ballidx,
                       w0, b0, s0, t0, w1, b1, s1, t1, w2, b2, s2, t2,
                       m0w, m0b, m0s, m0t, m1w, m1b, m1s, m1t);

  __syncthreads();
  stage_w64(sm.Wbuf, ew, t);
  stage_w64(Wb2, ew + 64 * 64, t);
  if (t < 128) {
    float v = es[t]; esf2[t] = v; bbf2[t] = v * eb[t] + et[t];
  }
  if (t < 64) sigl2[t] = sig[b * 64 + t];
  __syncthreads();
  {
#pragma unroll
    for (int nj = 0; nj < 8; ++nj)
      sm.X[(n0 + nj) * XS_ + lane] = sigl2[lane] * sm.H[(n0 + nj) * XS_ + lane];
  }
  final_gemm(sm.Wbuf, Wb2, sm.X, esf2, bbf2, zred, outf, b, s, t);
}

extern "C" void kernel_launch(void* const* d_in, const int* in_sizes, int n_in,
                              void* d_out, int out_size, void* d_ws, size_t ws_size,
                              hipStream_t stream) {
  const float* xyz    = (const float*)d_in[0];
  const float* points = (const float*)d_in[1];
  const float* w0 = (const float*)d_in[2],  *b0 = (const float*)d_in[3],  *s0 = (const float*)d_in[4],  *t0 = (const float*)d_in[5];
  const float* w1 = (const float*)d_in[6],  *b1 = (const float*)d_in[7],  *s1 = (const float*)d_in[8],  *t1 = (const float*)d_in[9];
  const float* w2 = (const float*)d_in[10], *b2 = (const float*)d_in[11], *s2 = (const float*)d_in[12], *t2 = (const float*)d_in[13];
  const float* m0w = (const float*)d_in[14], *m0b = (const float*)d_in[15], *m0s = (const float*)d_in[16], *m0t = (const float*)d_in[17];
  const float* m1w = (const float*)d_in[18], *m1b = (const float*)d_in[19], *m1s = (const float*)d_in[20], *m1t = (const float*)d_in[21];
  const float* ecak = (const float*)d_in[22];
  const float* ew = (const float*)d_in[23], *eb = (const float*)d_in[24], *es = (const float*)d_in[25], *et = (const float*)d_in[26];

  // ---- tiered workspace layout ----
  const size_t OFF_XYZT = 0;                 //  2,097,152 (B,N,4) f32
  const size_t OFF_NXF  = 2097152;           //    262,144 (B,S,4) f32
  const size_t OFF_BIDX = 2359296;           //  2,097,152 (B,S,32) i32 (fused: prog[18] lives here)
  const size_t OFF_PART = 4456448;           //  4,194,304 (B,S,64) f32
  const size_t OFF_SIG  = 8650752;           //      4,096 (B,64) f32
  const size_t OFF_PTST = 8654848;           // 33,554,432 (B,N,64) f32
  const size_t OFF_H2   = 42209280;          // 134,217,728 (B,S,32,64) f32
  const size_t NEED_PTST = OFF_H2;           // 42,209,280
  const size_t NEED_H2   = 176427008;

  const bool use_ptst = ws_size >= NEED_PTST;
  const bool use_h2   = ws_size >= NEED_H2;

  char* ws = (char*)d_ws;
  float4* xyzt    = (float4*)(ws + OFF_XYZT);
  float4* nxf     = (float4*)(ws + OFF_NXF);
  int*    ballidx = (int*)   (ws + OFF_BIDX);
  u32*    prog    = (u32*)   (ws + OFF_BIDX);   // shared region; exclusive per path
  float*  partials= (float*) (ws + OFF_PART);
  float*  sig     = (float*) (ws + OFF_SIG);
  float*  ptst    = (float*) (ws + OFF_PTST);
  float*  h2      = (float*) (ws + OFF_H2);

  float* out_xyz  = (float*)d_out;                          // (B,3,S) f32
  float* out_feat = (float*)d_out + (size_t)B_ * 3 * S_;    // (B,128,S) f32

  k_xyzt<<<dim3(N_ / 256, B_), 256, 0, stream>>>(xyz, xyzt, prog);
  if (use_ptst)
    k_ptst<<<dim3(N_ / 64, B_), 256, 0, stream>>>(points, ptst);

  if (use_h2) {
    // single fused kernel: fps + ball + chain + eca + final (no tail dispatches)
    k_fused<<<B_ + NWORK_, 1024, 0, stream>>>(xyzt, ptst, nxf, out_xyz, prog,
        w0, b0, s0, t0, w1, b1, s1, t1, w2, b2, s2, t2,
        m0w, m0b, m0s, m0t, m1w, m1b, m1s, m1t, h2, partials,
        ecak, ew, eb, es, et, sig, out_feat);
  } else if (use_ptst) {
    k_fps <<<B_, 1024, 0, stream>>>(xyzt, nxf, out_xyz);
    k_ball<<<(B_ * S_) / 4, 256, 0, stream>>>(xyzt, nxf, ballidx);
    k_chain<true, false><<<B_ * S_, 256, 0, stream>>>(xyzt, ptst, points, nxf, ballidx,
        w0, b0, s0, t0, w1, b1, s1, t1, w2, b2, s2, t2,
        m0w, m0b, m0s, m0t, m1w, m1b, m1s, m1t, h2, partials);
    k_eca<<<B_, 256, 0, stream>>>(partials, ecak, sig);
    k_final_rec<true><<<B_ * S_, 256, 0, stream>>>(xyzt, ptst, points, nxf, ballidx,
        w0, b0, s0, t0, w1, b1, s1, t1, w2, b2, s2, t2,
        m0w, m0b, m0s, m0t, m1w, m1b, m1s, m1t, sig, ew, eb, es, et, out_feat);
  } else {
    k_fps <<<B_, 1024, 0, stream>>>(xyzt, nxf, out_xyz);
    k_ball<<<(B_ * S_) / 4, 256, 0, stream>>>(xyzt, nxf, ballidx);
    k_chain<false, false><<<B_ * S_, 256, 0, stream>>>(xyzt, ptst, points, nxf, ballidx,
        w0, b0, s0, t0, w1, b1, s1, t1, w2, b2, s2, t2,
        m0w, m0b, m0s, m0t, m1w, m1b, m1s, m1t, h2, partials);
    k_eca<<<B_, 256, 0, stream>>>(partials, ecak, sig);
    k_final_rec<false><<<B_ * S_, 256, 0, stream>>>(xyzt, ptst, points, nxf, ballidx,
        w0, b0, s0, t0, w1, b1, s1, t1, w2, b2, s2, t2,
        m0w, m0b, m0s, m0t, m1w, m1b, m1s, m1t, sig, ew, eb, es, et, out_feat);
  }
}

// Round 11
// 1236.484 us; speedup vs baseline: 1.8602x; 1.0756x over previous
//
#include <hip/hip_runtime.h>

typedef unsigned int   u32;
typedef unsigned long long u64;
typedef float pkf2 __attribute__((ext_vector_type(2)));

#define B_  16
#define N_  8192
#define S_  1024
#define NS_ 32
#define XS_ 68   // [n][c] LDS row stride in floats (quad stride 17 == conflict-free)
#define NWORK_ 240
#define NCHUNK_ 4096   // 1024 s-values x 4 b-groups; each chunk = 4 tiles (one per subgroup)

// ============================================================================
// FINAL CONFIGURATION (session conclusion, measured 1240us twice: r2, r5)
//   k_xyzt + k_ptst (serial, ~30us)
//   k_fused: fps spine (~970us serial-latency floor, parked after r4-r14+r1
//            falsification sweeps) with ball+chain HIDDEN under it via
//            producer/consumer co-residency (saves ~250us of serialized work)
//   k_eca + k_final_h2 (~235us, LDS-instruction-throughput bound: r3-r10
//            falsified launch-overhead, bank-conflict, read-count, reg-W,
//            DVFS, and fusion theories; 8 tail variants all >= this bound;
//            bigger register blocking spills even at 128 VGPR (r6))
// ============================================================================

__device__ __forceinline__ float nanguard(float v) {
  u32 x = __float_as_uint(v);
  if ((x & 0x7F80u) == 0x7F80u) x ^= 0x0080u;
  return __uint_as_float(x);
}

// wave64 max via DPP (rocPRIM pattern)
__device__ __forceinline__ float wave_max_nonneg(float v) {
  int x = __float_as_int(v);
#define DPP_STEP(ctrl) \
  x = __float_as_int(fmaxf(__int_as_float(x), \
      __int_as_float(__builtin_amdgcn_update_dpp(0, x, (ctrl), 0xf, 0xf, true))))
  DPP_STEP(0x111);  // row_shr:1
  DPP_STEP(0x112);  // row_shr:2
  DPP_STEP(0x114);  // row_shr:4
  DPP_STEP(0x118);  // row_shr:8
  DPP_STEP(0x142);  // row_bcast15
  DPP_STEP(0x143);  // row_bcast31
#undef DPP_STEP
  return __int_as_float(__builtin_amdgcn_readlane(x, 63));
}

// ---------------- K0a: xyz (B,3,N) -> (B,N,4) f32 (+ zero fps progress) ------
__global__ __launch_bounds__(256) void k_xyzt(const float* __restrict__ xyz, float4* __restrict__ xyzt,
                                              u32* __restrict__ prog) {
  if (blockIdx.x == 0 && blockIdx.y == 0 && threadIdx.x < 16) prog[threadIdx.x] = 0u;
  int b = blockIdx.y;
  int i = blockIdx.x * 256 + threadIdx.x;
  const float* p = xyz + (size_t)b * 3 * N_;
  xyzt[(size_t)b * N_ + i] = make_float4(p[i], p[N_ + i], p[2 * N_ + i], 0.f);
}

// ---------------- K0b: points (B,64,N) -> (B,N,64) f32 ----------------
__global__ __launch_bounds__(256) void k_ptst(const float* __restrict__ pts, float* __restrict__ ptst) {
  __shared__ float tile[64][65];
  int b = blockIdx.y, n0 = blockIdx.x * 64, t = threadIdx.x;
  {
    int c = t >> 2, j0 = (t & 3) * 16;
    const float4* src = (const float4*)(pts + (size_t)b * 64 * N_ + (size_t)c * N_ + n0 + j0);
#pragma unroll
    for (int q = 0; q < 4; ++q) {
      float4 a = src[q];
      tile[c][j0 + 4*q + 0] = a.x; tile[c][j0 + 4*q + 1] = a.y;
      tile[c][j0 + 4*q + 2] = a.z; tile[c][j0 + 4*q + 3] = a.w;
    }
  }
  __syncthreads();
  {
    int n = t >> 2, c0 = (t & 3) * 16;
    float4* dv = (float4*)(ptst + ((size_t)b * N_ + n0 + n) * 64 + c0);
#pragma unroll
    for (int q = 0; q < 4; ++q)
      dv[q] = make_float4(tile[c0 + 4*q + 0][n], tile[c0 + 4*q + 1][n],
                          tile[c0 + 4*q + 2][n], tile[c0 + 4*q + 3][n]);
  }
}

// ---------------- fallback K1: furthest point sampling (r12 verbatim) --------
__global__ __launch_bounds__(1024)
__attribute__((amdgpu_waves_per_eu(4, 4)))
void k_fps(const float4* __restrict__ xyzt,
           float4* __restrict__ nxf,
           float* __restrict__ out_xyz) {
#pragma clang fp contract(off)
  __shared__ float4 ldsp[N_];
  __shared__ u64 slot[4];
  __shared__ int win_hist[S_];
  int b = blockIdx.x, t = threadIdx.x;
  const float4* p4 = xyzt + (size_t)b * N_;
  const float4* pp8 = p4 + t * 8;

  float4 q0 = pp8[0], q1 = pp8[1], q2 = pp8[2], q3 = pp8[3];
  float4 q4 = pp8[4], q5 = pp8[5], q6 = pp8[6], q7 = pp8[7];
  ldsp[t * 8 + 0] = q0; ldsp[t * 8 + 1] = q1; ldsp[t * 8 + 2] = q2; ldsp[t * 8 + 3] = q3;
  ldsp[t * 8 + 4] = q4; ldsp[t * 8 + 5] = q5; ldsp[t * 8 + 6] = q6; ldsp[t * 8 + 7] = q7;

#define DECLPAIR(P, A, B) \
  pkf2 px##P = {q##A.x, q##B.x}; pkf2 py##P = {q##A.y, q##B.y}; \
  pkf2 pz##P = {q##A.z, q##B.z}; pkf2 dm##P = {1e10f, 1e10f};
  DECLPAIR(01, 0, 1) DECLPAIR(23, 2, 3) DECLPAIR(45, 4, 5) DECLPAIR(67, 6, 7)
#undef DECLPAIR
#define PIN(P) asm volatile("" : "+v"(px##P), "+v"(py##P), "+v"(pz##P));
  PIN(01) PIN(23) PIN(45) PIN(67)
#undef PIN

  if (t == 0) {
    slot[0] = 8191ull;
    slot[1] = 0; slot[2] = 0; slot[3] = 0;
    win_hist[0] = 0;
  }
  __syncthreads();
  int lane = t & 63;
  for (int it = 1; it < S_; ++it) {
    u64 w = slot[(it - 1) & 3];
    int widx = 8191 - (int)(w & 0xFFFFFFFFull);
    if (t == 0) { win_hist[it - 1] = widx; slot[(it + 1) & 3] = 0; }
    float4 c = ldsp[widx & (N_ - 1)];
    pkf2 cx2 = {c.x, c.x}, cy2 = {c.y, c.y}, cz2 = {c.z, c.z};
#define UPDP(P) { \
    pkf2 dx = px##P - cx2; pkf2 dy = py##P - cy2; pkf2 dz = pz##P - cz2; \
    pkf2 xx = dx * dx; pkf2 yy = dy * dy; pkf2 zz = dz * dz; \
    pkf2 ss = xx + yy; pkf2 dd = ss + zz; \
    dm##P.x = fminf(dm##P.x, dd.x); dm##P.y = fminf(dm##P.y, dd.y); }
    UPDP(01) UPDP(23) UPDP(45) UPDP(67)
#undef UPDP
    float e0 = dm01.x, e1 = dm01.y, e2 = dm23.x, e3 = dm23.y;
    float e4 = dm45.x, e5 = dm45.y, e6 = dm67.x, e7 = dm67.y;
    float va0 = e1 > e0 ? e1 : e0; int ia0 = e1 > e0 ? 1 : 0;
    float va1 = e3 > e2 ? e3 : e2; int ia1 = e3 > e2 ? 3 : 2;
    float va2 = e5 > e4 ? e5 : e4; int ia2 = e5 > e4 ? 5 : 4;
    float va3 = e7 > e6 ? e7 : e6; int ia3 = e7 > e6 ? 7 : 6;
    float vb0 = va1 > va0 ? va1 : va0; int ib0 = va1 > va0 ? ia1 : ia0;
    float vb1 = va3 > va2 ? va3 : va2; int ib1 = va3 > va2 ? ia3 : ia2;
    float bv = vb1 > vb0 ? vb1 : vb0;  int bk = vb1 > vb0 ? ib1 : ib0;
    int bi = t * 8 + bk;
    float wm = wave_max_nonneg(bv);
    u64 msk = __ballot(bv == wm);
    int wl = __ffsll((long long)msk) - 1;
    int wbi = __builtin_amdgcn_readlane(bi, wl);
    if (lane == 0)
      atomicMax(&slot[it & 3],
                ((u64)__float_as_uint(wm) << 32) | (u64)(u32)(8191 - wbi));
    __syncthreads();
  }
  if (t == 0)
    win_hist[S_ - 1] = 8191 - (int)(slot[(S_ - 1) & 3] & 0xFFFFFFFFull);
  __syncthreads();
  {
    int wi = win_hist[t] & (N_ - 1);
    float4 c = ldsp[wi];
    nxf[(size_t)b * S_ + t] = c;
    float* o = out_xyz + (size_t)b * 3 * S_;
    o[t] = nanguard(c.x); o[S_ + t] = nanguard(c.y); o[2 * S_ + t] = nanguard(c.z);
  }
}

// ---------------- fallback K2: ball query ----------------
__global__ __launch_bounds__(256) void k_ball(const float4* __restrict__ xyzt,
                                              const float4* __restrict__ nxf,
                                              int* __restrict__ ballidx) {
  int gw = blockIdx.x * 4 + (threadIdx.x >> 6);
  int lane = threadIdx.x & 63;
  int b = gw >> 10, s = gw & 1023;
  float4 c = nxf[(size_t)b * S_ + s];
  const float4* pts = xyzt + (size_t)b * N_;
  int* out = ballidx + (size_t)gw * NS_;
  int cnt = 0, first = 0;
  bool havefirst = false;
  for (int chunk = 0; chunk < N_; chunk += 64) {
    float4 p = pts[chunk + lane];
    float dx = p.x - c.x, dy = p.y - c.y, dz = p.z - c.z;
    float d2 = __fadd_rn(__fadd_rn(__fmul_rn(dx, dx), __fmul_rn(dy, dy)), __fmul_rn(dz, dz));
    bool v = d2 <= 0.04f;
    u64 m = __ballot(v);
    if (m) {
      int pos = cnt + __popcll(m & ((1ull << lane) - 1ull));
      if (v && pos < NS_) out[pos] = chunk + lane;
      if (!havefirst) { first = chunk + (__ffsll((long long)m) - 1); havefirst = true; }
      cnt += __popcll(m);
      if (cnt >= NS_) break;
    }
  }
  if (cnt < NS_) {
    for (int p = cnt + lane; p < NS_; p += 64) out[p] = first;
  }
}

// ---------------- chain machinery (fallback path, r10 verbatim) --------------
struct ChainSm {
  float Wbuf[64 * XS_];
  float W1f[64 * 9];
  float W0f[8 * 4];
  float s2f[64], sm0f[64], sm1f[64];
  float bb0[8];
  float bb1[64], bb2[64], bm0[64], bm1[64];
  float X[32 * XS_];
  float H[32 * XS_];
  float scratch[384];
  int   idx_s[NS_];
};

__device__ __forceinline__ void stage_w64(float* Wbuf, const float* w, int t) {
  int c = t >> 2, q = (t & 3) * 16;
  const float4* src = (const float4*)(w + c * 64 + q);
  float4* dst = (float4*)(Wbuf + c * XS_ + q);
  dst[0] = src[0]; dst[1] = src[1]; dst[2] = src[2]; dst[3] = src[3];
}

template<bool RELU>
__device__ __forceinline__ void gemm64(const float* __restrict__ Wbuf,
                                       const float* __restrict__ Xin,
                                       float* __restrict__ Yout,
                                       const float* __restrict__ scl,
                                       const float* __restrict__ bia,
                                       int lane, int n0) {
  float acc[8] = {0,0,0,0,0,0,0,0};
#pragma unroll
  for (int k4 = 0; k4 < 16; ++k4) {
    float4 wq = *(const float4*)&Wbuf[lane * XS_ + k4 * 4];
#pragma unroll
    for (int nj = 0; nj < 8; ++nj) {
      float4 xq = *(const float4*)&Xin[(n0 + nj) * XS_ + k4 * 4];
      acc[nj] += wq.x * xq.x; acc[nj] += wq.y * xq.y;
      acc[nj] += wq.z * xq.z; acc[nj] += wq.w * xq.w;
    }
  }
  float sc = scl[lane], bi = bia[lane];
#pragma unroll
  for (int nj = 0; nj < 8; ++nj) {
    float v = sc * acc[nj] + bi;
    Yout[(n0 + nj) * XS_ + lane] = RELU ? fmaxf(v, 0.f) : v;
  }
}

template<bool USE_PTST>
__device__ __forceinline__ void chain_tile(ChainSm& sm, int b, int s, int bs,
    const float4* xyzt, const float* ptst, const float* points,
    const float4* nxf, const int* ballidx,
    const float* w0, const float* b0, const float* s0, const float* t0,
    const float* w1, const float* b1, const float* s1, const float* t1,
    const float* w2, const float* b2, const float* s2, const float* t2,
    const float* m0w, const float* m0b, const float* m0s, const float* m0t,
    const float* m1w, const float* m1b, const float* m1s, const float* m1t) {
  int t = threadIdx.x, lane = t & 63, g = t >> 6, n0 = g * 8;

  stage_w64(sm.Wbuf, w2, t);
  if (t < 64) {
    float v2 = s2[t];  sm.s2f[t] = v2;  sm.bb2[t] = v2 * b2[t] + t2[t];
    float vm0 = m0s[t]; sm.sm0f[t] = vm0; sm.bm0[t] = vm0 * m0b[t] + m0t[t];
    float vm1 = m1s[t]; sm.sm1f[t] = vm1; sm.bm1[t] = vm1 * m1b[t] + m1t[t];
    float v1 = s1[t];
#pragma unroll
    for (int k = 0; k < 8; ++k) sm.W1f[t * 9 + k] = v1 * w1[t * 8 + k];
    sm.bb1[t] = v1 * b1[t] + t1[t];
  }
  if (t < 8) {
    float v0 = s0[t];
#pragma unroll
    for (int k = 0; k < 3; ++k) sm.W0f[t * 4 + k] = v0 * w0[t * 3 + k];
    sm.bb0[t] = v0 * b0[t] + t0[t];
  }
  if (t < NS_) sm.idx_s[t] = ballidx[(size_t)bs * NS_ + t] & (N_ - 1);
  __syncthreads();                                   // B1

  {
    int n = t >> 3, c8 = (t & 7) * 8;
    int pi = sm.idx_s[n];
    if (USE_PTST) {
      const float4* v = (const float4*)(ptst + ((size_t)b * N_ + pi) * 64 + c8);
      float4* xr = (float4*)&sm.X[n * XS_ + c8];
      xr[0] = v[0]; xr[1] = v[1];
    } else {
      const float* pp = points + (size_t)b * 64 * N_ + (size_t)c8 * N_ + pi;
#pragma unroll
      for (int j = 0; j < 8; ++j) sm.X[n * XS_ + c8 + j] = pp[(size_t)j * N_];
    }
  }
  if (t < NS_) {
    float4 p = xyzt[(size_t)b * N_ + sm.idx_s[t]];
    float4 cc = nxf[(size_t)b * S_ + s];
    float* gx = &sm.scratch[256 + t * 4];
    gx[0] = p.x - cc.x; gx[1] = p.y - cc.y; gx[2] = p.z - cc.z;
  }
  __syncthreads();                                   // B2

  {
    int n = t >> 3, cc = t & 7;
    const float* gx = &sm.scratch[256 + n * 4];
    float a = sm.bb0[cc];
    a += sm.W0f[cc * 4 + 0] * gx[0];
    a += sm.W0f[cc * 4 + 1] * gx[1];
    a += sm.W0f[cc * 4 + 2] * gx[2];
    sm.scratch[n * 8 + cc] = fmaxf(a, 0.f);
  }
  {
#pragma unroll
    for (int nj = 0; nj < 8; ++nj) {
      float a = sm.bb1[lane];
      const float* p8 = &sm.scratch[(n0 + nj) * 8];
#pragma unroll
      for (int k = 0; k < 8; ++k) a += sm.W1f[lane * 9 + k] * p8[k];
      sm.X[(n0 + nj) * XS_ + lane] += a;
    }
  }
  gemm64<false>(sm.Wbuf, sm.X, sm.H, sm.s2f, sm.bb2, lane, n0);
  __syncthreads();                                   // B3
  stage_w64(sm.Wbuf, m0w, t);
  __syncthreads();                                   // B4
  gemm64<true>(sm.Wbuf, sm.H, sm.X, sm.sm0f, sm.bm0, lane, n0);
  __syncthreads();                                   // B5
  stage_w64(sm.Wbuf, m1w, t);
  __syncthreads();                                   // B6
  gemm64<true>(sm.Wbuf, sm.X, sm.H, sm.sm1f, sm.bm1, lane, n0);
}

// ---------------- fallback K3: chain pass ----------------
template<bool USE_PTST, bool WRITE_H2>
__global__ __launch_bounds__(256) void k_chain(
    const float4* __restrict__ xyzt, const float* __restrict__ ptst,
    const float* __restrict__ points,
    const float4* __restrict__ nxf, const int* __restrict__ ballidx,
    const float* w0, const float* b0, const float* s0, const float* t0,
    const float* w1, const float* b1, const float* s1, const float* t1,
    const float* w2, const float* b2, const float* s2, const float* t2,
    const float* m0w, const float* m0b, const float* m0s, const float* m0t,
    const float* m1w, const float* m1b, const float* m1s, const float* m1t,
    float* __restrict__ h2out, float* __restrict__ partials) {
  __shared__ ChainSm sm;
  int t = threadIdx.x, bs = blockIdx.x;
  int b = bs >> 10, s = bs & 1023;
  int lane = t & 63, g = t >> 6, n0 = g * 8;

  chain_tile<USE_PTST>(sm, b, s, bs, xyzt, ptst, points, nxf, ballidx,
                       w0, b0, s0, t0, w1, b1, s1, t1, w2, b2, s2, t2,
                       m0w, m0b, m0s, m0t, m1w, m1b, m1s, m1t);

  float* psum = sm.scratch;
  float lsum = 0.f;
#pragma unroll
  for (int nj = 0; nj < 8; ++nj) {
    float r = sm.H[(n0 + nj) * XS_ + lane];
    lsum += r;
    if (WRITE_H2)
      h2out[((size_t)bs * 32 + n0 + nj) * 64 + lane] = r;
  }
  psum[lane * 5 + g] = lsum;
  __syncthreads();                                   // B7
  if (t < 64) {
    float v = (psum[t * 5 + 0] + psum[t * 5 + 1]) + (psum[t * 5 + 2] + psum[t * 5 + 3]);
    partials[(size_t)bs * 64 + t] = v;
  }
}

// ---------------- fused fps + ball + chain (round-2 verbatim: best = 963us) ---
// Blocks 0..15: fps producers (r12 critical path, t==0 publishes nxf + prog).
// Blocks 16..255: workers consuming (s, b)-tiles paced by prog, gathering
// activations from the PRE-TRANSPOSED ptst (L3-resident, light coalesced
// reads: FETCH ~15MB). r3/r4 falsification: folding ptst into workers (+50us
// spine) and direct strided gather (+17us spine, FETCH 41MB) both lose --
// serial k_ptst (25us) + light gathers is the measured optimum.
struct ChainSub {
  float X[32 * XS_];
  float H[32 * XS_];
  float scratch[384];
  int   idx_s[NS_];
};
struct WkSm {
  float Wc2[64 * XS_];
  float Wm0[64 * XS_];
  float Wm1[64 * XS_];
  float W1f[64 * 9];
  float W0f[8 * 4];
  float s2f[64], sm0f[64], sm1f[64];
  float bb0[8];
  float bb1[64], bb2[64], bm0[64], bm1[64];
  ChainSub sub[4];
};
struct FpsSm {
  float4 ldsp[N_];
  u64 slot[4];
  int win_hist[S_];
};
union FusedSm { FpsSm f; WkSm w; };
static_assert(sizeof(FusedSm) <= 160 * 1024, "LDS overflow");

__global__ __launch_bounds__(1024)
__attribute__((amdgpu_waves_per_eu(4, 4)))
void k_fused(const float4* __restrict__ xyzt, const float* __restrict__ ptst,
             float4* __restrict__ nxf, float* __restrict__ out_xyz,
             u32* __restrict__ prog,
             const float* w0, const float* b0, const float* s0, const float* t0,
             const float* w1, const float* b1, const float* s1, const float* t1,
             const float* w2, const float* b2, const float* s2, const float* t2,
             const float* m0w, const float* m0b, const float* m0s, const float* m0t,
             const float* m1w, const float* m1b, const float* m1s, const float* m1t,
             float* __restrict__ h2out, float* __restrict__ partials) {
  __shared__ FusedSm smu;
  int t = threadIdx.x;

  if (blockIdx.x < B_) {
    // ================= fps producer =================
#pragma clang fp contract(off)
    FpsSm& fs = smu.f;
    int b = blockIdx.x;
    const float4* p4 = xyzt + (size_t)b * N_;
    const float4* pp8 = p4 + t * 8;

    float4 q0 = pp8[0], q1 = pp8[1], q2 = pp8[2], q3 = pp8[3];
    float4 q4 = pp8[4], q5 = pp8[5], q6 = pp8[6], q7 = pp8[7];
    fs.ldsp[t * 8 + 0] = q0; fs.ldsp[t * 8 + 1] = q1; fs.ldsp[t * 8 + 2] = q2; fs.ldsp[t * 8 + 3] = q3;
    fs.ldsp[t * 8 + 4] = q4; fs.ldsp[t * 8 + 5] = q5; fs.ldsp[t * 8 + 6] = q6; fs.ldsp[t * 8 + 7] = q7;

#define DECLPAIR(P, A, B) \
    pkf2 px##P = {q##A.x, q##B.x}; pkf2 py##P = {q##A.y, q##B.y}; \
    pkf2 pz##P = {q##A.z, q##B.z}; pkf2 dm##P = {1e10f, 1e10f};
    DECLPAIR(01, 0, 1) DECLPAIR(23, 2, 3) DECLPAIR(45, 4, 5) DECLPAIR(67, 6, 7)
#undef DECLPAIR
#define PIN(P) asm volatile("" : "+v"(px##P), "+v"(py##P), "+v"(pz##P));
    PIN(01) PIN(23) PIN(45) PIN(67)
#undef PIN

    if (t == 0) {
      fs.slot[0] = 8191ull;
      fs.slot[1] = 0; fs.slot[2] = 0; fs.slot[3] = 0;
      fs.win_hist[0] = 0;
    }
    __syncthreads();
    int lane = t & 63;
    for (int it = 1; it < S_; ++it) {
      u64 w = fs.slot[(it - 1) & 3];
      int widx = 8191 - (int)(w & 0xFFFFFFFFull);
      float4 c = fs.ldsp[widx & (N_ - 1)];
      if (t == 0) {
        fs.win_hist[it - 1] = widx; fs.slot[(it + 1) & 3] = 0;
        // publish BEFORE this iter's store: outstanding stores are >=1 iter
        // old -> release's vmcnt drain is effectively free.
        if ((it & 15) == 0)
          __hip_atomic_store(&prog[b], (u32)(it - 1), __ATOMIC_RELEASE, __HIP_MEMORY_SCOPE_AGENT);
        nxf[(size_t)b * S_ + (it - 1)] = c;
      }
      pkf2 cx2 = {c.x, c.x}, cy2 = {c.y, c.y}, cz2 = {c.z, c.z};
#define UPDP(P) { \
      pkf2 dx = px##P - cx2; pkf2 dy = py##P - cy2; pkf2 dz = pz##P - cz2; \
      pkf2 xx = dx * dx; pkf2 yy = dy * dy; pkf2 zz = dz * dz; \
      pkf2 ss = xx + yy; pkf2 dd = ss + zz; \
      dm##P.x = fminf(dm##P.x, dd.x); dm##P.y = fminf(dm##P.y, dd.y); }
      UPDP(01) UPDP(23) UPDP(45) UPDP(67)
#undef UPDP
      float e0 = dm01.x, e1 = dm01.y, e2 = dm23.x, e3 = dm23.y;
      float e4 = dm45.x, e5 = dm45.y, e6 = dm67.x, e7 = dm67.y;
      float va0 = e1 > e0 ? e1 : e0; int ia0 = e1 > e0 ? 1 : 0;
      float va1 = e3 > e2 ? e3 : e2; int ia1 = e3 > e2 ? 3 : 2;
      float va2 = e5 > e4 ? e5 : e4; int ia2 = e5 > e4 ? 5 : 4;
      float va3 = e7 > e6 ? e7 : e6; int ia3 = e7 > e6 ? 7 : 6;
      float vb0 = va1 > va0 ? va1 : va0; int ib0 = va1 > va0 ? ia1 : ia0;
      float vb1 = va3 > va2 ? va3 : va2; int ib1 = va3 > va2 ? ia3 : ia2;
      float bv = vb1 > vb0 ? vb1 : vb0;  int bk = vb1 > vb0 ? ib1 : ib0;
      int bi = t * 8 + bk;
      float wm = wave_max_nonneg(bv);
      u64 msk = __ballot(bv == wm);
      int wl = __ffsll((long long)msk) - 1;
      int wbi = __builtin_amdgcn_readlane(bi, wl);
      if (lane == 0)
        atomicMax(&fs.slot[it & 3],
                  ((u64)__float_as_uint(wm) << 32) | (u64)(u32)(8191 - wbi));
      __syncthreads();
    }
    if (t == 0) {
      int wl_ = 8191 - (int)(fs.slot[(S_ - 1) & 3] & 0xFFFFFFFFull);
      fs.win_hist[S_ - 1] = wl_;
      float4 c = fs.ldsp[wl_ & (N_ - 1)];
      nxf[(size_t)b * S_ + (S_ - 1)] = c;
    }
    __syncthreads();
    {
      int wi = fs.win_hist[t] & (N_ - 1);
      float4 c = fs.ldsp[wi];
      float* o = out_xyz + (size_t)b * 3 * S_;
      o[t] = nanguard(c.x); o[S_ + t] = nanguard(c.y); o[2 * S_ + t] = nanguard(c.z);
    }
    if (t == 0)
      __hip_atomic_store(&prog[b], (u32)S_, __ATOMIC_RELEASE, __HIP_MEMORY_SCOPE_AGENT);
    return;
  }

  // ================= worker =================
  WkSm& wk = smu.w;
  int w = blockIdx.x - B_;
  // stage all weights once per block (no per-tile re-staging)
  if (t < 256) {
    stage_w64(wk.Wc2, w2, t);
    stage_w64(wk.Wm0, m0w, t);
    stage_w64(wk.Wm1, m1w, t);
  }
  if (t < 64) {
    float v2 = s2[t];  wk.s2f[t] = v2;  wk.bb2[t] = v2 * b2[t] + t2[t];
    float vm0 = m0s[t]; wk.sm0f[t] = vm0; wk.bm0[t] = vm0 * m0b[t] + m0t[t];
    float vm1 = m1s[t]; wk.sm1f[t] = vm1; wk.bm1[t] = vm1 * m1b[t] + m1t[t];
    float v1 = s1[t];
#pragma unroll
    for (int k = 0; k < 8; ++k) wk.W1f[t * 9 + k] = v1 * w1[t * 8 + k];
    wk.bb1[t] = v1 * b1[t] + t1[t];
  }
  if (t < 8) {
    float v0 = s0[t];
#pragma unroll
    for (int k = 0; k < 3; ++k) wk.W0f[t * 4 + k] = v0 * w0[t * 3 + k];
    wk.bb0[t] = v0 * b0[t] + t0[t];
  }
  __syncthreads();

  int sg = t >> 8, tid = t & 255, lane = t & 63, g2 = (t >> 6) & 3, n0 = g2 * 8;
  ChainSub& cs = wk.sub[sg];

  for (int ck = w; ck < NCHUNK_; ck += NWORK_) {
    int s = ck >> 2, bg = ck & 3, b = bg * 4 + sg;
    if (t == 0) {
      int bbase = bg * 4;
#pragma unroll
      for (int j = 0; j < 4; ++j) {
        while (__hip_atomic_load(&prog[bbase + j], __ATOMIC_RELAXED, __HIP_MEMORY_SCOPE_AGENT) < (u32)(s + 1))
          __builtin_amdgcn_s_sleep(32);
      }
      (void)__hip_atomic_load(&prog[bbase], __ATOMIC_ACQUIRE, __HIP_MEMORY_SCOPE_AGENT);
    }
    __syncthreads();                                 // BAR A (data for s visible)

    float4 cc;
    if (g2 == 0) {
      cc = nxf[(size_t)b * S_ + s];
      const float4* pts = xyzt + (size_t)b * N_;
      int cnt = 0, first = 0;
      bool havefirst = false;
      for (int chunk = 0; chunk < N_; chunk += 64) {
        float4 p = pts[chunk + lane];
        float dx = p.x - cc.x, dy = p.y - cc.y, dz = p.z - cc.z;
        float d2 = __fadd_rn(__fadd_rn(__fmul_rn(dx, dx), __fmul_rn(dy, dy)), __fmul_rn(dz, dz));
        bool v = d2 <= 0.04f;
        u64 m = __ballot(v);
        if (m) {
          int pos = cnt + __popcll(m & ((1ull << lane) - 1ull));
          if (v && pos < NS_) cs.idx_s[pos] = chunk + lane;
          if (!havefirst) { first = chunk + (__ffsll((long long)m) - 1); havefirst = true; }
          cnt += __popcll(m);
          if (cnt >= NS_) break;
        }
      }
      if (cnt < NS_) {
        for (int p = cnt + lane; p < NS_; p += 64) cs.idx_s[p] = first;
      }
    }
    __syncthreads();                                 // BAR B (idx_s ready)

    {
      int n = tid >> 3, c8 = (tid & 7) * 8;
      int pi = cs.idx_s[n];
      const float4* v = (const float4*)(ptst + ((size_t)b * N_ + pi) * 64 + c8);
      float4* xr = (float4*)&cs.X[n * XS_ + c8];
      xr[0] = v[0]; xr[1] = v[1];
    }
    if (tid < NS_) {
      float4 p = xyzt[(size_t)b * N_ + cs.idx_s[tid]];
      float* gx = &cs.scratch[256 + tid * 4];
      gx[0] = p.x - cc.x; gx[1] = p.y - cc.y; gx[2] = p.z - cc.z;
    }
    __syncthreads();                                 // BAR C (GX cross-wave)

    {
      int n = tid >> 3, ch = tid & 7;
      const float* gx = &cs.scratch[256 + n * 4];
      float a = wk.bb0[ch];
      a += wk.W0f[ch * 4 + 0] * gx[0];
      a += wk.W0f[ch * 4 + 1] * gx[1];
      a += wk.W0f[ch * 4 + 2] * gx[2];
      cs.scratch[n * 8 + ch] = fmaxf(a, 0.f);
    }
    {
#pragma unroll
      for (int nj = 0; nj < 8; ++nj) {
        float a = wk.bb1[lane];
        const float* p8 = &cs.scratch[(n0 + nj) * 8];
#pragma unroll
        for (int k = 0; k < 8; ++k) a += wk.W1f[lane * 9 + k] * p8[k];
        cs.X[(n0 + nj) * XS_ + lane] += a;
      }
    }
    gemm64<false>(wk.Wc2, cs.X, cs.H, wk.s2f, wk.bb2, lane, n0);
    gemm64<true >(wk.Wm0, cs.H, cs.X, wk.sm0f, wk.bm0, lane, n0);
    gemm64<true >(wk.Wm1, cs.X, cs.H, wk.sm1f, wk.bm1, lane, n0);

    int bs = (b << 10) | s;
    float lsum = 0.f;
#pragma unroll
    for (int nj = 0; nj < 8; ++nj) {
      float r = cs.H[(n0 + nj) * XS_ + lane];
      lsum += r;
      h2out[((size_t)bs * 32 + n0 + nj) * 64 + lane] = r;
    }
    __syncthreads();                                 // BAR D (scratch free for psum)
    cs.scratch[lane * 5 + g2] = lsum;
    __syncthreads();                                 // BAR E
    if (tid < 64) {
      float v = (cs.scratch[tid * 5 + 0] + cs.scratch[tid * 5 + 1]) +
                (cs.scratch[tid * 5 + 2] + cs.scratch[tid * 5 + 3]);
      partials[(size_t)bs * 64 + tid] = v;
    }
  }
}

// ---------------- K4: mean + ECA conv + sigmoid -> sig (B,64) ----------------
__global__ __launch_bounds__(256) void k_eca(const float* __restrict__ partials,
                                             const float* __restrict__ ecak,
                                             float* __restrict__ sig) {
  __shared__ float red[64 * 5];
  __shared__ float yy[66];
  int b = blockIdx.x, t = threadIdx.x;
  int c = t & 63, sg = t >> 6;
  float acc = 0.f;
  for (int s = sg; s < S_; s += 4) acc += partials[((size_t)b * S_ + s) * 64 + c];
  red[c * 5 + sg] = acc;
  __syncthreads();
  if (t < 64) {
    float v = (red[t * 5 + 0] + red[t * 5 + 1]) + (red[t * 5 + 2] + red[t * 5 + 3]);
    yy[t + 1] = v * (1.f / 32768.f);
  }
  if (t == 64) { yy[0] = 0.f; yy[65] = 0.f; }
  __syncthreads();
  if (t < 64) {
    float gv = ecak[0] * yy[t] + ecak[1] * yy[t + 1] + ecak[2] * yy[t + 2];
    sig[b * 64 + t] = 1.f / (1.f + expf(-gv));
  }
}

// ---------------- K5a: fast final, 4ch x 4row decomposition (r5: best) -------
// LDS-instruction-throughput bound (~230us): 128 ds_read_b128/thread-tile at
// ~12cyc throughput == ~165us/CU floor. r3-r10 falsified: launch overhead
// (persistent grid, r3), bank conflicts (XS_=68 already conflict-free, r4),
// reg-resident W (r4, occupancy loss), bigger reg blocking (r6: spills even at
// 128 VGPR), DVFS/launch-boundary (r10: warm-clock in-kernel final was SLOWER
// at 305us). This decomposition is the measured optimum of the family.
__global__ __launch_bounds__(256) void k_final_h2(const float* __restrict__ h2,
                                                  const float* __restrict__ sig,
                                                  const float* ew, const float* eb,
                                                  const float* es, const float* et,
                                                  float* __restrict__ outf) {
  __shared__ float Wh[128 * XS_];
  __shared__ float esf[128], bbf[128], sigl[64];
  __shared__ float X2[32 * XS_];
  __shared__ float zred[128 * 9];
  int t = threadIdx.x, bs = blockIdx.x;
  int b = bs >> 10, s = bs & 1023;
  {
    int c2 = t >> 1, h = (t & 1) * 32;
    const float4* src = (const float4*)(ew + c2 * 64 + h);
    float4* dst = (float4*)(Wh + c2 * XS_ + h);
#pragma unroll
    for (int j = 0; j < 8; ++j) dst[j] = src[j];
  }
  if (t < 128) {
    float v = es[t]; esf[t] = v; bbf[t] = v * eb[t] + et[t];
  }
  if (t < 64) sigl[t] = sig[b * 64 + t];
  __syncthreads();
  { // gather + gate -> X2[n][c]
    int n = t >> 3, c8 = (t & 7) * 8;
    const float4* v = (const float4*)(h2 + ((size_t)bs * 32 + n) * 64 + c8);
    float4 a = v[0], bq = v[1];
    a.x *= sigl[c8 + 0]; a.y *= sigl[c8 + 1]; a.z *= sigl[c8 + 2]; a.w *= sigl[c8 + 3];
    bq.x *= sigl[c8 + 4]; bq.y *= sigl[c8 + 5]; bq.z *= sigl[c8 + 6]; bq.w *= sigl[c8 + 7];
    float4* xr = (float4*)&X2[n * XS_ + c8];
    xr[0] = a; xr[1] = bq;
  }
  // same-wave write->read ordering: no barrier needed here
  {
    int ch = t & 31, r = t >> 5;
    const float* W0p = &Wh[(size_t)(ch     ) * XS_];
    const float* W1p = &Wh[(size_t)(ch + 32) * XS_];
    const float* W2p = &Wh[(size_t)(ch + 64) * XS_];
    const float* W3p = &Wh[(size_t)(ch + 96) * XS_];
    const float* X0p = &X2[(size_t)(4*r + 0) * XS_];
    const float* X1p = &X2[(size_t)(4*r + 1) * XS_];
    const float* X2p = &X2[(size_t)(4*r + 2) * XS_];
    const float* X3p = &X2[(size_t)(4*r + 3) * XS_];
    float acc[4][4];
#pragma unroll
    for (int i = 0; i < 4; ++i)
#pragma unroll
      for (int j = 0; j < 4; ++j) acc[i][j] = 0.f;
#pragma unroll
    for (int k4 = 0; k4 < 16; ++k4) {
      float4 w0q = *(const float4*)&W0p[k4 * 4];
      float4 w1q = *(const float4*)&W1p[k4 * 4];
      float4 w2q = *(const float4*)&W2p[k4 * 4];
      float4 w3q = *(const float4*)&W3p[k4 * 4];
      float4 x0q = *(const float4*)&X0p[k4 * 4];
      float4 x1q = *(const float4*)&X1p[k4 * 4];
      float4 x2q = *(const float4*)&X2p[k4 * 4];
      float4 x3q = *(const float4*)&X3p[k4 * 4];
#define DOT4(ci, wq, rj, xq) \
      acc[ci][rj] += wq.x * xq.x; acc[ci][rj] += wq.y * xq.y; \
      acc[ci][rj] += wq.z * xq.z; acc[ci][rj] += wq.w * xq.w;
#define ROW4(ci, wq) DOT4(ci, wq, 0, x0q) DOT4(ci, wq, 1, x1q) DOT4(ci, wq, 2, x2q) DOT4(ci, wq, 3, x3q)
      ROW4(0, w0q) ROW4(1, w1q) ROW4(2, w2q) ROW4(3, w3q)
#undef ROW4
#undef DOT4
    }
    // max over this thread's 4 rows; bn scale > 0, affine monotone
#pragma unroll
    for (int ci = 0; ci < 4; ++ci) {
      float m = fmaxf(fmaxf(acc[ci][0], acc[ci][1]), fmaxf(acc[ci][2], acc[ci][3]));
      int c = ch + ci * 32;
      zred[c * 9 + r] = esf[c] * m + bbf[c];
    }
  }
  __syncthreads();
  if (t < 128) {
    const float* z = &zred[t * 9];
    float m = fmaxf(fmaxf(fmaxf(z[0], z[1]), fmaxf(z[2], z[3])),
                    fmaxf(fmaxf(z[4], z[5]), fmaxf(z[6], z[7])));
    outf[((size_t)b * 128 + t) * S_ + s] = nanguard(m);
  }
}

// dual 64-row GEMM + max epilogue (fallback finals)
__device__ __forceinline__ void final_gemm(const float* __restrict__ WA,
                                           const float* __restrict__ WB,
                                           const float* __restrict__ X2,
                                           const float* __restrict__ esf,
                                           const float* __restrict__ bbf,
                                           float* __restrict__ zred,
                                           float* __restrict__ outf,
                                           int b, int s, int t) {
  int lane = t & 63, g = t >> 6, n0 = g * 8;
  float aA[8] = {0,0,0,0,0,0,0,0}, aB[8] = {0,0,0,0,0,0,0,0};
#pragma unroll
  for (int k4 = 0; k4 < 16; ++k4) {
    float4 wqA = *(const float4*)&WA[lane * XS_ + k4 * 4];
    float4 wqB = *(const float4*)&WB[lane * XS_ + k4 * 4];
#pragma unroll
    for (int nj = 0; nj < 8; ++nj) {
      float4 xq = *(const float4*)&X2[(n0 + nj) * XS_ + k4 * 4];
      aA[nj] += wqA.x * xq.x; aA[nj] += wqA.y * xq.y;
      aA[nj] += wqA.z * xq.z; aA[nj] += wqA.w * xq.w;
      aB[nj] += wqB.x * xq.x; aB[nj] += wqB.y * xq.y;
      aB[nj] += wqB.z * xq.z; aB[nj] += wqB.w * xq.w;
    }
  }
  float mA = aA[0], mB = aB[0];
#pragma unroll
  for (int j = 1; j < 8; ++j) { mA = fmaxf(mA, aA[j]); mB = fmaxf(mB, aB[j]); }
  zred[lane * 5 + g]        = esf[lane] * mA + bbf[lane];
  zred[(lane + 64) * 5 + g] = esf[lane + 64] * mB + bbf[lane + 64];
  __syncthreads();
  if (t < 128) {
    float m = fmaxf(fmaxf(zred[t * 5 + 0], zred[t * 5 + 1]),
                    fmaxf(zred[t * 5 + 2], zred[t * 5 + 3]));
    outf[((size_t)b * 128 + t) * S_ + s] = nanguard(m);
  }
}

// ---------------- K5b: recompute final (fallback) ----------------
template<bool USE_PTST>
__global__ __launch_bounds__(256) void k_final_rec(
    const float4* __restrict__ xyzt, const float* __restrict__ ptst,
    const float* __restrict__ points,
    const float4* __restrict__ nxf, const int* __restrict__ ballidx,
    const float* w0, const float* b0, const float* s0, const float* t0,
    const float* w1, const float* b1, const float* s1, const float* t1,
    const float* w2, const float* b2, const float* s2, const float* t2,
    const float* m0w, const float* m0b, const float* m0s, const float* m0t,
    const float* m1w, const float* m1b, const float* m1s, const float* m1t,
    const float* __restrict__ sig,
    const float* ew, const float* eb, const float* es, const float* et,
    float* __restrict__ outf) {
  __shared__ ChainSm sm;
  __shared__ float Wb2[64 * XS_];
  __shared__ float esf2[128], bbf2[128], sigl2[64];
  __shared__ float zred[128 * 5];
  int t = threadIdx.x, bs = blockIdx.x;
  int b = bs >> 10, s = bs & 1023;
  int lane = t & 63, g = t >> 6, n0 = g * 8;

  chain_tile<USE_PTST>(sm, b, s, bs, xyzt, ptst, points, nxf, ballidx,
                       w0, b0, s0, t0, w1, b1, s1, t1, w2, b2, s2, t2,
                       m0w, m0b, m0s, m0t, m1w, m1b, m1s, m1t);

  __syncthreads();
  stage_w64(sm.Wbuf, ew, t);
  stage_w64(Wb2, ew + 64 * 64, t);
  if (t < 128) {
    float v = es[t]; esf2[t] = v; bbf2[t] = v * eb[t] + et[t];
  }
  if (t < 64) sigl2[t] = sig[b * 64 + t];
  __syncthreads();
  {
#pragma unroll
    for (int nj = 0; nj < 8; ++nj)
      sm.X[(n0 + nj) * XS_ + lane] = sigl2[lane] * sm.H[(n0 + nj) * XS_ + lane];
  }
  final_gemm(sm.Wbuf, Wb2, sm.X, esf2, bbf2, zred, outf, b, s, t);
}

extern "C" void kernel_launch(void* const* d_in, const int* in_sizes, int n_in,
                              void* d_out, int out_size, void* d_ws, size_t ws_size,
                              hipStream_t stream) {
  const float* xyz    = (const float*)d_in[0];
  const float* points = (const float*)d_in[1];
  const float* w0 = (const float*)d_in[2],  *b0 = (const float*)d_in[3],  *s0 = (const float*)d_in[4],  *t0 = (const float*)d_in[5];
  const float* w1 = (const float*)d_in[6],  *b1 = (const float*)d_in[7],  *s1 = (const float*)d_in[8],  *t1 = (const float*)d_in[9];
  const float* w2 = (const float*)d_in[10], *b2 = (const float*)d_in[11], *s2 = (const float*)d_in[12], *t2 = (const float*)d_in[13];
  const float* m0w = (const float*)d_in[14], *m0b = (const float*)d_in[15], *m0s = (const float*)d_in[16], *m0t = (const float*)d_in[17];
  const float* m1w = (const float*)d_in[18], *m1b = (const float*)d_in[19], *m1s = (const float*)d_in[20], *m1t = (const float*)d_in[21];
  const float* ecak = (const float*)d_in[22];
  const float* ew = (const float*)d_in[23], *eb = (const float*)d_in[24], *es = (const float*)d_in[25], *et = (const float*)d_in[26];

  // ---- tiered workspace layout ----
  const size_t OFF_XYZT = 0;                 //  2,097,152 (B,N,4) f32
  const size_t OFF_NXF  = 2097152;           //    262,144 (B,S,4) f32
  const size_t OFF_BIDX = 2359296;           //  2,097,152 (B,S,32) i32 (fused: prog[16] lives here)
  const size_t OFF_PART = 4456448;           //  4,194,304 (B,S,64) f32
  const size_t OFF_SIG  = 8650752;           //      4,096 (B,64) f32
  const size_t OFF_PTST = 8654848;           // 33,554,432 (B,N,64) f32
  const size_t OFF_H2   = 42209280;          // 134,217,728 (B,S,32,64) f32
  const size_t NEED_PTST = OFF_H2;           // 42,209,280
  const size_t NEED_H2   = 176427008;

  const bool use_ptst = ws_size >= NEED_PTST;
  const bool use_h2   = ws_size >= NEED_H2;

  char* ws = (char*)d_ws;
  float4* xyzt    = (float4*)(ws + OFF_XYZT);
  float4* nxf     = (float4*)(ws + OFF_NXF);
  int*    ballidx = (int*)   (ws + OFF_BIDX);
  u32*    prog    = (u32*)   (ws + OFF_BIDX);   // shared region; exclusive per path
  float*  partials= (float*) (ws + OFF_PART);
  float*  sig     = (float*) (ws + OFF_SIG);
  float*  ptst    = (float*) (ws + OFF_PTST);
  float*  h2      = (float*) (ws + OFF_H2);

  float* out_xyz  = (float*)d_out;                          // (B,3,S) f32
  float* out_feat = (float*)d_out + (size_t)B_ * 3 * S_;    // (B,128,S) f32

  k_xyzt<<<dim3(N_ / 256, B_), 256, 0, stream>>>(xyz, xyzt, prog);
  if (use_ptst)
    k_ptst<<<dim3(N_ / 64, B_), 256, 0, stream>>>(points, ptst);

  if (use_h2) {
    // fused fps + ball + chain: chain work hides under the 900us fps spine
    k_fused<<<B_ + NWORK_, 1024, 0, stream>>>(xyzt, ptst, nxf, out_xyz, prog,
        w0, b0, s0, t0, w1, b1, s1, t1, w2, b2, s2, t2,
        m0w, m0b, m0s, m0t, m1w, m1b, m1s, m1t, h2, partials);
    k_eca<<<B_, 256, 0, stream>>>(partials, ecak, sig);
    k_final_h2<<<B_ * S_, 256, 0, stream>>>(h2, sig, ew, eb, es, et, out_feat);
  } else if (use_ptst) {
    k_fps <<<B_, 1024, 0, stream>>>(xyzt, nxf, out_xyz);
    k_ball<<<(B_ * S_) / 4, 256, 0, stream>>>(xyzt, nxf, ballidx);
    k_chain<true, false><<<B_ * S_, 256, 0, stream>>>(xyzt, ptst, points, nxf, ballidx,
        w0, b0, s0, t0, w1, b1, s1, t1, w2, b2, s2, t2,
        m0w, m0b, m0s, m0t, m1w, m1b, m1s, m1t, h2, partials);
    k_eca<<<B_, 256, 0, stream>>>(partials, ecak, sig);
    k_final_rec<true><<<B_ * S_, 256, 0, stream>>>(xyzt, ptst, points, nxf, ballidx,
        w0, b0, s0, t0, w1, b1, s1, t1, w2, b2, s2, t2,
        m0w, m0b, m0s, m0t, m1w, m1b, m1s, m1t, sig, ew, eb, es, et, out_feat);
  } else {
    k_fps <<<B_, 1024, 0, stream>>>(xyzt, nxf, out_xyz);
    k_ball<<<(B_ * S_) / 4, 256, 0, stream>>>(xyzt, nxf, ballidx);
    k_chain<false, false><<<B_ * S_, 256, 0, stream>>>(xyzt, ptst, points, nxf, ballidx,
        w0, b0, s0, t0, w1, b1, s1, t1, w2, b2, s2, t2,
        m0w, m0b, m0s, m0t, m1w, m1b, m1s, m1t, h2, partials);
    k_eca<<<B_, 256, 0, stream>>>(partials, ecak, sig);
    k_final_rec<false><<<B_ * S_, 256, 0, stream>>>(xyzt, ptst, points, nxf, ballidx,
        w0, b0, s0, t0, w1, b1, s1, t1, w2, b2, s2, t2,
        m0w, m0b, m0s, m0t, m1w, m1b, m1s, m1t, sig, ew, eb, es, et, out_feat);
  }
}